// Round 6
// baseline (660.513 us; speedup 1.0000x reference)
//
#include <hip/hip_runtime.h>
#include <hip/hip_bf16.h>
#include <stdint.h>

#define DINL __device__ __forceinline__

DINL float bf2f(__hip_bfloat16 v) { return __bfloat162float(v); }
DINL __hip_bfloat16 f2bf(float v) { return __float2bfloat16(v); }
DINL float bflo(unsigned int u) { return __uint_as_float(u << 16); }
DINL float bfhi(unsigned int u) { return __uint_as_float(u & 0xffff0000u); }

DINL float loadf(float v) { return v; }
DINL float loadf(__hip_bfloat16 v) { return __bfloat162float(v); }

typedef __attribute__((ext_vector_type(8))) short bf16x8;
typedef __attribute__((ext_vector_type(4))) float f32x4;

// async global->LDS DMA, 16 B per lane. LDS dest must be wave-uniform base + lane*16
// (true for all call sites: addresses are base + tid*16 + const).
DINL void gld_lds16(const void* g, void* l) {
  __builtin_amdgcn_global_load_lds(
      (const __attribute__((address_space(1))) unsigned int*)g,
      (__attribute__((address_space(3))) unsigned int*)l, 16, 0, 0);
}

// ---------------- ws layout ----------------
// fp32 region (float offsets):
#define O_WTE1 0         // [2][3][9][32] fp32 blocked (te1 VALU conv)   1728
#define O_WG2  1792      // [6][64]                                      384
#define O_SS   2304      // [4][256][9]  border-class emb sums           9216
#define O_INT  11520     // [4][16384] intensity                         65536
// fp32 region ends at float 77056 = byte 308224
// bf16/byte offsets:
#define BO_W2B   308224u   // w_f2 bf16 MFMA *A-fragment* layout [24][4][8][64][8]  786432 B
#define BO_TE2B 1094656u   // w_te2 bf16 [2][2][9][64][32]      147456 B
#define BO_WG1B 1242112u   // w_g1  bf16 [1][4][9][64][32]      147456 B
#define BO_WF1B 1389568u   // w_f1  bf16 [4][4][9][64][32]      589824 B (ends 1979392)
#define BO_TEX  4194304u   // tex bf16 pixel-major [4][16384][128]  16.78 MB
#define BO_F1   20971520u  // f1  bf16 pixel-major [4][16384][256]  33.55 MB
#define BO_PING 54525952u  // fp32 [4*24*16384]  6.29 MB
#define BO_PONG 60817408u
#define BO_W    67108864u  // weights bf16 ROW-MAJOR [4][24][128 row][49 tap][128 w]  154.14 MB
#define BO_T1   BO_W             // t1 bf16 pixel-major [4][16384][64] (dead before W written)

// ---------------- prep: weight re-layouts (bf16 MFMA blocks) + SS table ----------------
__global__ __launch_bounds__(256) void prep_kernel(
    const float* __restrict__ w_te1, const float* __restrict__ w_te2,
    const float* __restrict__ w_g1,  const float* __restrict__ w_f1,
    const float* __restrict__ w_f2,  const float* __restrict__ w_g2,
    const float* __restrict__ emb,   const int* __restrict__ labels,
    float* __restrict__ wsf)
{
  const int gid = blockIdx.x * 256 + threadIdx.x;
  const int stride = gridDim.x * 256;
  const int A0 = 1728, A1 = A0 + 393216, A2 = A1 + 73728, A3 = A2 + 73728,
            A4 = A3 + 294912, A5 = A4 + 384;
  __hip_bfloat16* w2b  = (__hip_bfloat16*)((char*)wsf + BO_W2B);
  __hip_bfloat16* te2b = (__hip_bfloat16*)((char*)wsf + BO_TE2B);
  __hip_bfloat16* g1b  = (__hip_bfloat16*)((char*)wsf + BO_WG1B);
  __hip_bfloat16* f1b  = (__hip_bfloat16*)((char*)wsf + BO_WF1B);
  for (int i = gid; i < A5; i += stride) {
    if (i < A0) {
      int s = i; int o = s / 27; int r = s - o * 27; int ic = r / 9; int t = r - ic * 9;
      wsf[O_WTE1 + (((o >> 5) * 3 + ic) * 9 + t) * 32 + (o & 31)] = w_te1[s];
    } else if (i < A1) {
      // w_f2 [1176][256] fp32 -> bf16 A-fragment layout [c24][mt4][ks8][lane64][8]
      int s = i - A0;
      int j = s & 7; int lane = (s >> 3) & 63; int ks = (s >> 9) & 7;
      int mt = (s >> 12) & 3; int c = s >> 14;
      int tap = mt * 16 + (lane & 15);
      int k = ks * 32 + (lane >> 4) * 8 + j;
      float v = (tap < 49) ? w_f2[(c * 49 + tap) * 256 + k] : 0.f;
      w2b[s] = f2bf(v);
    } else if (i < A2) {
      int s = i - A1;
      int k = s & 31; int n = (s >> 5) & 63; int u = s >> 11;
      int t = u % 9; int v = u / 9; int kc = v & 1; int ocg = v >> 1;
      te2b[s] = f2bf(w_te2[((ocg * 64 + n) * 64 + kc * 32 + k) * 9 + t]);
    } else if (i < A3) {
      int s = i - A2;
      int k = s & 31; int n = (s >> 5) & 63; int u = s >> 11;
      int t = u % 9; int kc = u / 9;
      g1b[s] = f2bf(w_g1[(n * 128 + kc * 32 + k) * 9 + t]);
    } else if (i < A4) {
      int s = i - A3;
      int k = s & 31; int n = (s >> 5) & 63; int u = s >> 11;
      int t = u % 9; int v = u / 9; int kc = v & 3; int ocg = v >> 2;
      f1b[s] = f2bf(w_f1[((ocg * 64 + n) * 256 + kc * 32 + k) * 9 + t]);
    } else {
      int s = i - A4;
      wsf[O_WG2 + s] = w_g2[s];
    }
  }
  // SS: 16 slots per (b,o); slot s sums i in [s*8, s*8+8); shfl-reduce across slots.
  if (gid < 16384) {
    const int g = gid >> 4, slot = gid & 15;
    const int b = g >> 8, o = g & 255;
    const int lab = labels[b];
    float St[9];
#pragma unroll
    for (int t = 0; t < 9; ++t) St[t] = 0.f;
#pragma unroll 2
    for (int k = 0; k < 8; ++k) {
      const int i = slot * 8 + k;
      const float e = emb[lab * 128 + i];
      const float* wr = w_f1 + (size_t)(o * 256 + 128 + i) * 9;
#pragma unroll
      for (int t = 0; t < 9; ++t) St[t] += wr[t] * e;
    }
#pragma unroll
    for (int d = 1; d < 16; d <<= 1)
#pragma unroll
      for (int t = 0; t < 9; ++t) St[t] += __shfl_xor(St[t], d, 64);
    if (slot == 0) {
#pragma unroll
      for (int ch = 0; ch < 3; ++ch)
#pragma unroll
        for (int cw = 0; cw < 3; ++cw) {
          float sum = 0.f;
#pragma unroll
          for (int t = 0; t < 9; ++t) {
            int kh = t / 3, kw = t - kh * 3;
            bool ok = !(ch == 0 && kh == 0) && !(ch == 2 && kh == 2) &&
                      !(cw == 0 && kw == 0) && !(cw == 2 && kw == 2);
            if (ok) sum += St[t];
          }
          wsf[O_SS + g * 9 + ch * 3 + cw] = sum;
        }
    }
  }
}

// ---------------- small VALU 3x3 conv (te1 only: ICH=3) ----------------
template<typename TIn, int ICH, bool PIXMAJOR>
__global__ __launch_bounds__(256, 2) void conv3x3_kernel(
    const TIn* __restrict__ in, const float* __restrict__ wf,
    const float* __restrict__ bias,
    __hip_bfloat16* __restrict__ out, const int och_total)
{
  constexpr int CH = (ICH < 16) ? ICH : 16;
  constexpr int NCHUNK = ICH / CH;
  __shared__ TIn sIn[CH][18][20];
  const int tid = threadIdx.x;
  const int b = blockIdx.z;
  const int ob = blockIdx.y;
  const int och0 = ob * 32;
  const int tileY = blockIdx.x >> 3, tileX = blockIdx.x & 7;
  const int ty = tid >> 4, tx = tid & 15;
  const int h = tileY * 16 + ty, w = tileX * 16 + tx;
  const int h0 = tileY * 16 - 1, w0 = tileX * 16 - 1;

  float acc[32];
#pragma unroll
  for (int o = 0; o < 32; ++o) acc[o] = bias[och0 + o];

  for (int cc = 0; cc < NCHUNK; ++cc) {
    if (cc) __syncthreads();
    for (int e = tid; e < CH * 324; e += 256) {
      int ic = e / 324, r = e - ic * 324;
      int y = r / 18, x = r - y * 18;
      int gh = h0 + y, gw = w0 + x;
      TIn v = TIn(0.f);
      if ((unsigned)gh < 128u && (unsigned)gw < 128u)
        v = in[((b * ICH + cc * CH + ic) << 14) + (gh << 7) + gw];
      sIn[ic][y][x] = v;
    }
    __syncthreads();
#pragma unroll 1
    for (int ic = 0; ic < CH; ++ic) {
      const float* wrow = wf + (ob * ICH + cc * CH + ic) * 288;  // [9][32]
#pragma unroll
      for (int t = 0; t < 9; ++t) {
        const int kh = t / 3, kw = t - kh * 3;
        const float v = loadf(sIn[ic][ty + kh][tx + kw]);
#pragma unroll
        for (int o = 0; o < 32; ++o)
          acc[o] = fmaf(wrow[t * 32 + o], v, acc[o]);
      }
    }
  }

  const int pix = (h << 7) + w;
  if constexpr (!PIXMAJOR) {
#pragma unroll
    for (int o = 0; o < 32; ++o)
      out[((b * och_total + och0 + o) << 14) + pix] = f2bf(fmaxf(acc[o], 0.f));
  } else {
    union { uint4 u4[4]; __hip_bfloat16 hh[32]; } pk;
#pragma unroll
    for (int o = 0; o < 32; ++o) pk.hh[o] = f2bf(fmaxf(acc[o], 0.f));
    uint4* dst = reinterpret_cast<uint4*>(out + ((size_t)(b << 14) + pix) * och_total + och0);
#pragma unroll
    for (int i = 0; i < 4; ++i) dst[i] = pk.u4[i];
  }
}

// ---------------- MFMA implicit-GEMM 3x3 conv (zero pad), pixel-major bf16 ----------------
// GATE=true (gate1 instance, 64 och, ocg grid = 1): fuses the former gate2_kernel —
// fragments round-trip through an LDS overlay (smem reused after the MFMA loop),
// then per-thread 64->6 dot + sigmoid + class_gate/intensity/condition writes.
// Numerics identical to the split version: g1 quantized to bf16 at the same point.
template<int ICH, bool ADD_SS, bool GATE>
__global__ __launch_bounds__(256, 2) void conv3x3_mfma_kernel(
    const __hip_bfloat16* __restrict__ in, const __hip_bfloat16* __restrict__ wb,
    const float* __restrict__ bias, const float* __restrict__ SS,
    __hip_bfloat16* __restrict__ out, const int och_total,
    const float* __restrict__ wg2, const float* __restrict__ b_g2,
    const int* __restrict__ labels, const float* __restrict__ ci,
    float* __restrict__ out_cg, float* __restrict__ out_cond,
    float* __restrict__ inten)
{
  constexpr int NKC = ICH / 32;
  __shared__ __hip_bfloat16 smem[36000];   // sH 324*40 | sW 9*64*40  (72 KB)
#define SHX(pos, k) smem[(pos) * 40 + (k)]
#define SWX(t, n, k) smem[12960 + (((t) * 64 + (n)) * 40) + (k)]
  const int tid = threadIdx.x, b = blockIdx.z, ocg = blockIdx.y;
  const int tileY = blockIdx.x >> 3, tileX = blockIdx.x & 7;
  const int h0 = tileY * 16 - 1, w0 = tileX * 16 - 1;
  const int wave = tid >> 6, lane = tid & 63, m16 = lane & 15, quad = lane >> 4;

  f32x4 acc[4][4];
#pragma unroll
  for (int i = 0; i < 4; ++i)
#pragma unroll
    for (int j = 0; j < 4; ++j) acc[i][j] = f32x4{0.f, 0.f, 0.f, 0.f};

  for (int kc = 0; kc < NKC; ++kc) {
    if (kc) __syncthreads();
    for (int e = tid; e < 1296; e += 256) {
      int pos = e >> 2, q = e & 3;
      int y = pos / 18, x = pos - y * 18;
      int gh = h0 + y, gw = w0 + x;
      uint4 v = uint4{0u, 0u, 0u, 0u};
      if ((unsigned)gh < 128u && (unsigned)gw < 128u)
        v = *(const uint4*)(in + ((size_t)((b << 14) + (gh << 7) + gw)) * ICH + kc * 32 + q * 8);
      *(uint4*)&SHX(pos, q * 8) = v;
    }
    const uint4* wsrc = (const uint4*)(wb + ((size_t)(ocg * NKC + kc)) * 9 * 64 * 32);
    for (int e = tid; e < 2304; e += 256) {
      int q = e & 3, n = (e >> 2) & 63, t = e >> 8;
      *(uint4*)&SWX(t, n, q * 8) = wsrc[e];
    }
    __syncthreads();
#pragma unroll
    for (int t = 0; t < 9; ++t) {
      const int dy = t / 3, dx = t - dy * 3;
      bf16x8 bfr[4];
#pragma unroll
      for (int nt = 0; nt < 4; ++nt)
        bfr[nt] = *(const bf16x8*)&SWX(t, nt * 16 + m16, quad * 8);
#pragma unroll
      for (int mi = 0; mi < 4; ++mi) {
        const int py = wave * 4 + mi;
        const bf16x8 afr = *(const bf16x8*)&SHX((py + dy) * 18 + dx + m16, quad * 8);
#pragma unroll
        for (int nt = 0; nt < 4; ++nt)
          acc[mi][nt] = __builtin_amdgcn_mfma_f32_16x16x32_bf16(afr, bfr[nt], acc[mi][nt], 0, 0, 0);
      }
    }
  }

  float bv[4];
#pragma unroll
  for (int nt = 0; nt < 4; ++nt) bv[nt] = bias[ocg * 64 + nt * 16 + m16];

  if constexpr (GATE) {
    // stage bf16-quantized ReLU'd fragments into LDS overlay sG[256 px][68]
    __syncthreads();   // all MFMA smem reads done
    __hip_bfloat16* sG = smem;
#pragma unroll
    for (int mi = 0; mi < 4; ++mi)
#pragma unroll
      for (int nt = 0; nt < 4; ++nt) {
        const int och = nt * 16 + m16;
#pragma unroll
        for (int r = 0; r < 4; ++r) {
          const int p = (wave * 4 + mi) * 16 + quad * 4 + r;
          sG[p * 68 + och] = f2bf(fmaxf(acc[mi][nt][r] + bv[nt], 0.f));
        }
      }
    __syncthreads();
    // per-thread gate2: pixel p = tid
    const int p = tid;
    float a6[6];
#pragma unroll
    for (int k = 0; k < 6; ++k) a6[k] = b_g2[k];
#pragma unroll
    for (int i8 = 0; i8 < 8; ++i8) {
      const bf16x8 v8 = *(const bf16x8*)&sG[p * 68 + i8 * 8];
#pragma unroll
      for (int j = 0; j < 8; ++j) {
        const float v = bf2f(((const __hip_bfloat16*)&v8)[j]);
#pragma unroll
        for (int k = 0; k < 6; ++k)
          a6[k] = fmaf(wg2[k * 64 + i8 * 8 + j], v, a6[k]);
      }
    }
    const int lab = labels[b];
    float gate[6], gl = 0.f;
#pragma unroll
    for (int k = 0; k < 6; ++k) {
      gate[k] = 1.f / (1.f + __expf(-a6[k]));
      gl = (k == lab) ? gate[k] : gl;
    }
    const float civ = ci[lab];
    const float it = gl * civ;
    const int h = tileY * 16 + (p >> 4), w = tileX * 16 + (p & 15);
    const int pix = (h << 7) + w;
#pragma unroll
    for (int k = 0; k < 6; ++k)
      out_cg[((b * 6 + k) << 14) + pix] = (k == lab) ? gate[k] : 0.f;
    inten[(b << 14) + pix] = it;
    out_cond[(b << 14) + pix] = it * gl;
    return;
  }

#pragma unroll
  for (int mi = 0; mi < 4; ++mi) {
    const int py = wave * 4 + mi;
    const int h = tileY * 16 + py;
    const int chc = (h == 0) ? 0 : ((h == 127) ? 2 : 1);
#pragma unroll
    for (int nt = 0; nt < 4; ++nt) {
      float sr0 = 0.f, sr1 = 0.f, sr2 = 0.f;
      if constexpr (ADD_SS) {
        const float* sp = SS + ((size_t)(b << 8) + (ocg * 64 + nt * 16 + m16)) * 9;
        sr0 = sp[chc * 3 + 0]; sr1 = sp[chc * 3 + 1]; sr2 = sp[chc * 3 + 2];
      }
      const int och = ocg * 64 + nt * 16 + m16;
#pragma unroll
      for (int r = 0; r < 4; ++r) {
        const int px = quad * 4 + r;
        const int w = tileX * 16 + px;
        float v = acc[mi][nt][r] + bv[nt];
        if constexpr (ADD_SS)
          v += (w == 0) ? sr0 : ((w == 127) ? sr2 : sr1);
        v = fmaxf(v, 0.f);
        out[((size_t)((b << 14) + (h << 7) + w)) * och_total + och] = f2bf(v);
      }
    }
  }
#undef SHX
#undef SWX
}

// ---------------- fused GEMM+softmax v13: single sW buffer, 5 blocks/CU ----------
// R20 theory: v10/v12 counters show NOTHING saturated (MfmaUtil 22, VALU 34,
// HBM 28%, LDS ~36% of peak, conflicts ~0) -> latency/barrier-bound at ~2.5
// blocks/CU (LDS 46.6 KB limited). v13 drops the sW double buffer: LDS 29.7 KB
// -> 5 blocks/CU (launch_bounds(256,5), VGPR cap 102 >= 68 in use). Per-unit
// schedule: MFMA -> barrier (sW reads done) -> DMA issue -> [softmax at h==1
// overlaps DMA latency] -> barrier (drain). Inter-block wave overlap (m114)
// covers the in-block serialization; softmax numerics identical.
__global__ __launch_bounds__(256, 5) void gemm_softmax_kernel(
    const __hip_bfloat16* __restrict__ f1, const __hip_bfloat16* __restrict__ w2b,
    const float* __restrict__ b_f2, const float* __restrict__ inten,
    __hip_bfloat16* __restrict__ wout)
{
  __shared__ __hip_bfloat16 sW[8192];          // 16 KB: [mtl2][ks8][lane64][8]
  __shared__ __hip_bfloat16 sT[49][136];       // softmax out: [tap][pix] (+8 pad)
  const int tid = threadIdx.x;
  const int pix0 = blockIdx.x * 128;           // one (b,row): 128 px
  const int c0 = blockIdx.y * 8;                 // 8 channels per block
  const int wave = tid >> 6, lane = tid & 63;
  const int n16 = lane & 15, quad = lane >> 4;
  const int p0 = pix0 + wave * 16 + n16;         // pixel group 0
  const int p1 = p0 + 64;                        // pixel group 1

  // B fragments (f1, channel-invariant): 2 pixel groups x 8 ks-steps (64 VGPR)
  bf16x8 bfr0[8], bfr1[8];
#pragma unroll
  for (int ks = 0; ks < 8; ++ks) {
    bfr0[ks] = *(const bf16x8*)(f1 + (size_t)p0 * 256 + ks * 32 + quad * 8);
    bfr1[ks] = *(const bf16x8*)(f1 + (size_t)p1 * 256 + ks * 32 + quad * 8);
  }

  const float s0v = inten[p0], s1v = inten[p1];
  const int ob = pix0 >> 14, row = (pix0 >> 7) & 127;

  // unit u (0..15) = channel c0+(u>>1), mt-pair (u&1): 16 KB at w2b + unit<<12 elems
#define W2U(u) ((const uint4*)(w2b + ((((size_t)c0 + ((u) >> 1)) * 4 + (((u) & 1) << 1)) << 12)))

  // prologue: DMA unit 0
  {
    const uint4* s0 = W2U(0);
    uint4* d0 = (uint4*)&sW[0];
#pragma unroll
    for (int j = 0; j < 4; ++j)
      gld_lds16(s0 + tid + j * 256, d0 + tid + j * 256);
  }
  __syncthreads();   // drain: buf holds unit 0

#pragma unroll 1
  for (int cl = 0; cl < 8; ++cl) {
    const int c = c0 + cl;
    f32x4 ac0[4], ac1[4];
#pragma unroll
    for (int mt = 0; mt < 4; ++mt) { ac0[mt] = f32x4{0.f,0.f,0.f,0.f}; ac1[mt] = f32x4{0.f,0.f,0.f,0.f}; }

#pragma unroll
    for (int h = 0; h < 2; ++h) {
      const int u = cl * 2 + h;
      // compute unit u (mt = 2h, 2h+1) from sW: 32 MFMA
#pragma unroll
      for (int ks = 0; ks < 8; ++ks) {
        const bf16x8 a0 = *(const bf16x8*)(&sW[0] + ((ks) * 64 + lane) * 8);
        const bf16x8 a1 = *(const bf16x8*)(&sW[0] + ((8 + ks) * 64 + lane) * 8);
        ac0[h * 2 + 0] = __builtin_amdgcn_mfma_f32_16x16x32_bf16(a0, bfr0[ks], ac0[h * 2 + 0], 0, 0, 0);
        ac1[h * 2 + 0] = __builtin_amdgcn_mfma_f32_16x16x32_bf16(a0, bfr1[ks], ac1[h * 2 + 0], 0, 0, 0);
        ac0[h * 2 + 1] = __builtin_amdgcn_mfma_f32_16x16x32_bf16(a1, bfr0[ks], ac0[h * 2 + 1], 0, 0, 0);
        ac1[h * 2 + 1] = __builtin_amdgcn_mfma_f32_16x16x32_bf16(a1, bfr1[ks], ac1[h * 2 + 1], 0, 0, 0);
      }
      __syncthreads();   // all waves done reading sW (WAR vs DMA below)
      // DMA next unit into the (single) buffer
      if (u < 15) {
        const uint4* sn = W2U(u + 1);
        uint4* dn = (uint4*)&sW[0];
#pragma unroll
        for (int j = 0; j < 4; ++j)
          gld_lds16(sn + tid + j * 256, dn + tid + j * 256);
      }
      if (h == 0) __syncthreads();   // drain DMA before next unit's MFMA
      // at h==1 the drain happens at the post-softmax barrier (softmax hides DMA)
    }

    // softmax per pixel group; taps 0..47 all valid (mt<3), tap 48 scalar on quad==0
    const float b48 = b_f2[c * 49 + 48];
#pragma unroll
    for (int g = 0; g < 2; ++g) {
      f32x4* ac = g ? ac1 : ac0;
      const float s = g ? s1v : s0v;
      float mx = -3.4e38f;
#pragma unroll
      for (int mt = 0; mt < 3; ++mt)
#pragma unroll
        for (int r = 0; r < 4; ++r) {
          const float lv = (ac[mt][r] + b_f2[c * 49 + mt * 16 + quad * 4 + r]) * s;
          ac[mt][r] = lv;
          mx = fmaxf(mx, lv);
        }
      const float v48 = (ac[3][0] + b48) * s;
      if (quad == 0) mx = fmaxf(mx, v48);
      mx = fmaxf(mx, __shfl_xor(mx, 16, 64));
      mx = fmaxf(mx, __shfl_xor(mx, 32, 64));
      float sum = 0.f;
#pragma unroll
      for (int mt = 0; mt < 3; ++mt)
#pragma unroll
        for (int r = 0; r < 4; ++r) {
          const float e = __expf(ac[mt][r] - mx);
          ac[mt][r] = e;
          sum += e;
        }
      const float e48 = (quad == 0) ? __expf(v48 - mx) : 0.f;
      sum += e48;
      sum += __shfl_xor(sum, 16, 64);
      sum += __shfl_xor(sum, 32, 64);
      const float rs = 1.f / sum;

      const int px = wave * 16 + n16 + g * 64;
#pragma unroll
      for (int mt = 0; mt < 3; ++mt)
#pragma unroll
        for (int r = 0; r < 4; ++r)
          sT[mt * 16 + quad * 4 + r][px] = f2bf(ac[mt][r] * rs);
      if (quad == 0) sT[48][px] = f2bf(e48 * rs);
    }
    __syncthreads();   // drains the h==1 DMA + sT visible

    // contiguous store: one 12.25 KB block per (b,c,row) = 784 uint4
    __hip_bfloat16* wob = wout + ((size_t)((ob * 24 + c) * 128 + row)) * 6272;
    for (int e = tid; e < 784; e += 256) {
      const int tap = e >> 4, qq = e & 15;
      *(uint4*)(wob + tap * 128 + qq * 8) = *(const uint4*)&sT[tap][qq * 8];
    }
    // WAR on sT: next channel's softmax writes happen after the next two
    // in-loop barriers -> all stores complete first
  }
#undef W2U
}

// ---------------- diffusion step v5: row-major weights, dense per-row streams ----------
// wts layout [b][c][row][tap][128]: thread (ty,tx8)'s 49 loads walk a 12.25 KB window
// at 256 B stride; each 16-lane row-group consumes its window completely ->
// near-sequential DRAM access instead of 49 streams at 32 KB stride.
__global__ __launch_bounds__(256) void diff_kernel(
    const float* __restrict__ lin, const __hip_bfloat16* __restrict__ wts,
    float* __restrict__ lout)
{
  __shared__ float sT[22][136];   // 16+6 rows, 128+6 cols (136: row 16B-aligned)
  const int bc = blockIdx.y;
  const int h0 = blockIdx.x * 16;
  const int tid = threadIdx.x;
  for (int e = tid; e < 22 * 134; e += 256) {
    int y = e / 134, x = e - y * 134;
    int gh = min(max(h0 - 3 + y, 0), 127), gw = min(max(x - 3, 0), 127);
    sT[y][x] = lin[(bc << 14) + (gh << 7) + gw];
  }
  __syncthreads();
  const int tx8 = (tid & 15) * 8;  // first of 8 pixels in w
  const int ty = tid >> 4;         // row 0..15
  const int h = h0 + ty;
  const __hip_bfloat16* wp = wts + ((size_t)(bc * 128 + h)) * 6272 + tx8;
  float a[8];
#pragma unroll
  for (int j = 0; j < 8; ++j) a[j] = 0.f;
#pragma unroll
  for (int kh = 0; kh < 7; ++kh) {
    const float* row = &sT[ty + kh][tx8];
    float r[16];
    *(f32x4*)&r[0]  = *(const f32x4*)(row);
    *(f32x4*)&r[4]  = *(const f32x4*)(row + 4);
    *(f32x4*)&r[8]  = *(const f32x4*)(row + 8);
    *(f32x4*)&r[12] = *(const f32x4*)(row + 12);
#pragma unroll
    for (int kw = 0; kw < 7; ++kw) {
      const int t = kh * 7 + kw;
      const uint4 wq = *(const uint4*)(wp + t * 128);
      a[0] = fmaf(bflo(wq.x), r[kw + 0], a[0]);
      a[1] = fmaf(bfhi(wq.x), r[kw + 1], a[1]);
      a[2] = fmaf(bflo(wq.y), r[kw + 2], a[2]);
      a[3] = fmaf(bfhi(wq.y), r[kw + 3], a[3]);
      a[4] = fmaf(bflo(wq.z), r[kw + 4], a[4]);
      a[5] = fmaf(bfhi(wq.z), r[kw + 5], a[5]);
      a[6] = fmaf(bflo(wq.w), r[kw + 6], a[6]);
      a[7] = fmaf(bfhi(wq.w), r[kw + 7], a[7]);
    }
  }
  float* dst = lout + (bc << 14) + (h << 7) + tx8;
  *(f32x4*)dst       = f32x4{a[0], a[1], a[2], a[3]};
  *(f32x4*)(dst + 4) = f32x4{a[4], a[5], a[6], a[7]};
}

// ---------------- orchestration ----------------
extern "C" void kernel_launch(void* const* d_in, const int* in_sizes, int n_in,
                              void* d_out, int out_size, void* d_ws, size_t ws_size,
                              hipStream_t stream)
{
  const float* depth = (const float*)d_in[0];
  const float* texf  = (const float*)d_in[1];
  const int*   labels= (const int*)d_in[2];
  const float* w_te1 = (const float*)d_in[3];
  const float* b_te1 = (const float*)d_in[4];
  const float* w_te2 = (const float*)d_in[5];
  const float* b_te2 = (const float*)d_in[6];
  const float* emb   = (const float*)d_in[7];
  const float* w_f1  = (const float*)d_in[8];
  const float* b_f1  = (const float*)d_in[9];
  const float* w_f2  = (const float*)d_in[10];
  const float* b_f2  = (const float*)d_in[11];
  const float* w_g1  = (const float*)d_in[12];
  const float* b_g1  = (const float*)d_in[13];
  const float* w_g2  = (const float*)d_in[14];
  const float* b_g2  = (const float*)d_in[15];
  const float* ci    = (const float*)d_in[16];

  char*  ws  = (char*)d_ws;
  float* wsf = (float*)d_ws;
  __hip_bfloat16* w2bf  = (__hip_bfloat16*)(ws + BO_W2B);
  __hip_bfloat16* te2bf = (__hip_bfloat16*)(ws + BO_TE2B);
  __hip_bfloat16* g1bf  = (__hip_bfloat16*)(ws + BO_WG1B);
  __hip_bfloat16* f1bf  = (__hip_bfloat16*)(ws + BO_WF1B);
  __hip_bfloat16* tex   = (__hip_bfloat16*)(ws + BO_TEX);
  __hip_bfloat16* f1    = (__hip_bfloat16*)(ws + BO_F1);
  float* ping           = (float*)(ws + BO_PING);
  float* pong           = (float*)(ws + BO_PONG);
  __hip_bfloat16* wts   = (__hip_bfloat16*)(ws + BO_W);
  __hip_bfloat16* t1    = (__hip_bfloat16*)(ws + BO_T1);

  float* out      = (float*)d_out;
  float* out_enh  = out;                 // [4][24][128][128]
  float* out_cg   = out + 1572864;       // [4][6][128][128]
  float* out_cond = out + 1966080;       // [4][1][128][128]

  prep_kernel<<<512, 256, 0, stream>>>(w_te1, w_te2, w_g1, w_f1, w_f2, w_g2, emb, labels, wsf);
  conv3x3_kernel<float, 3, true><<<dim3(64, 2, 4), 256, 0, stream>>>(texf, wsf + O_WTE1, b_te1, t1, 64);
  conv3x3_mfma_kernel<64,  false, false><<<dim3(64, 2, 4), 256, 0, stream>>>(
      t1, te2bf, b_te2, nullptr, tex, 128,
      nullptr, nullptr, nullptr, nullptr, nullptr, nullptr, nullptr);
  // gate1 conv + fused gate2
  conv3x3_mfma_kernel<128, false, true><<<dim3(64, 1, 4), 256, 0, stream>>>(
      tex, g1bf, b_g1, nullptr, nullptr, 64,
      wsf + O_WG2, b_g2, labels, ci, out_cg, out_cond, wsf + O_INT);
  conv3x3_mfma_kernel<128, true, false><<<dim3(64, 4, 4), 256, 0, stream>>>(
      tex, f1bf, b_f1, wsf + O_SS, f1, 256,
      nullptr, nullptr, nullptr, nullptr, nullptr, nullptr, nullptr);
  gemm_softmax_kernel<<<dim3(512, 3), 256, 0, stream>>>(f1, w2bf, b_f2, wsf + O_INT, wts);

  dim3 dgrid(8, 96);
  diff_kernel<<<dgrid, 256, 0, stream>>>(depth, wts, ping);
  diff_kernel<<<dgrid, 256, 0, stream>>>(ping, wts, pong);
  diff_kernel<<<dgrid, 256, 0, stream>>>(pong, wts, ping);
  diff_kernel<<<dgrid, 256, 0, stream>>>(ping, wts, pong);
  diff_kernel<<<dgrid, 256, 0, stream>>>(pong, wts, ping);
  diff_kernel<<<dgrid, 256, 0, stream>>>(ping, wts, pong);
  diff_kernel<<<dgrid, 256, 0, stream>>>(pong, wts, ping);
  diff_kernel<<<dgrid, 256, 0, stream>>>(ping, wts, out_enh);
}

// Round 9
// 493.075 us; speedup vs baseline: 1.3396x; 1.3396x over previous
//
#include <hip/hip_runtime.h>
#include <hip/hip_bf16.h>
#include <stdint.h>

#define DINL __device__ __forceinline__

DINL float bf2f(__hip_bfloat16 v) { return __bfloat162float(v); }
DINL __hip_bfloat16 f2bf(float v) { return __float2bfloat16(v); }
DINL float bflo(unsigned int u) { return __uint_as_float(u << 16); }
DINL float bfhi(unsigned int u) { return __uint_as_float(u & 0xffff0000u); }

DINL float loadf(float v) { return v; }
DINL float loadf(__hip_bfloat16 v) { return __bfloat162float(v); }

typedef __attribute__((ext_vector_type(8))) short bf16x8;
typedef __attribute__((ext_vector_type(4))) float f32x4;

// async global->LDS DMA, 16 B per lane. LDS dest must be wave-uniform base + lane*16
// (true for all call sites: addresses are base + tid*16 + const).
DINL void gld_lds16(const void* g, void* l) {
  __builtin_amdgcn_global_load_lds(
      (const __attribute__((address_space(1))) unsigned int*)g,
      (__attribute__((address_space(3))) unsigned int*)l, 16, 0, 0);
}

// ---------------- ws layout ----------------
// fp32 region (float offsets):
#define O_WTE1 0         // [2][3][9][32] fp32 blocked (te1 VALU conv)   1728
#define O_WG2  1792      // [6][64]                                      384
#define O_SS   2304      // [4][256][9]  border-class emb sums           9216
#define O_INT  11520     // [4][16384] intensity                         65536
// fp32 region ends at float 77056 = byte 308224
// bf16/byte offsets:
#define BO_W2B   308224u   // w_f2 bf16 MFMA *A-fragment* layout [24][4][8][64][8]  786432 B
#define BO_TE2B 1094656u   // w_te2 bf16 [2][2][9][64][32]      147456 B
#define BO_WG1B 1242112u   // w_g1  bf16 [1][4][9][64][32]      147456 B
#define BO_WF1B 1389568u   // w_f1  bf16 [4][4][9][64][32]      589824 B (ends 1979392)
#define BO_TEX  4194304u   // tex bf16 pixel-major [4][16384][128]  16.78 MB
#define BO_F1   20971520u  // f1  bf16 pixel-major [4][16384][256]  33.55 MB
#define BO_PING 54525952u  // fp32 [4*24*16384]  6.29 MB
#define BO_PONG 60817408u
#define BO_W    67108864u  // weights bf16 ROW-MAJOR [4][24][128 row][49 tap][128 w]  154.14 MB
#define BO_T1   BO_W             // t1 bf16 pixel-major [4][16384][64] (dead before W written)

// ---------------- prep: weight re-layouts (bf16 MFMA blocks) + SS table ----------------
__global__ __launch_bounds__(256) void prep_kernel(
    const float* __restrict__ w_te1, const float* __restrict__ w_te2,
    const float* __restrict__ w_g1,  const float* __restrict__ w_f1,
    const float* __restrict__ w_f2,  const float* __restrict__ w_g2,
    const float* __restrict__ emb,   const int* __restrict__ labels,
    float* __restrict__ wsf)
{
  const int gid = blockIdx.x * 256 + threadIdx.x;
  const int stride = gridDim.x * 256;
  const int A0 = 1728, A1 = A0 + 393216, A2 = A1 + 73728, A3 = A2 + 73728,
            A4 = A3 + 294912, A5 = A4 + 384;
  __hip_bfloat16* w2b  = (__hip_bfloat16*)((char*)wsf + BO_W2B);
  __hip_bfloat16* te2b = (__hip_bfloat16*)((char*)wsf + BO_TE2B);
  __hip_bfloat16* g1b  = (__hip_bfloat16*)((char*)wsf + BO_WG1B);
  __hip_bfloat16* f1b  = (__hip_bfloat16*)((char*)wsf + BO_WF1B);
  for (int i = gid; i < A5; i += stride) {
    if (i < A0) {
      int s = i; int o = s / 27; int r = s - o * 27; int ic = r / 9; int t = r - ic * 9;
      wsf[O_WTE1 + (((o >> 5) * 3 + ic) * 9 + t) * 32 + (o & 31)] = w_te1[s];
    } else if (i < A1) {
      // w_f2 [1176][256] fp32 -> bf16 A-fragment layout [c24][mt4][ks8][lane64][8]
      int s = i - A0;
      int j = s & 7; int lane = (s >> 3) & 63; int ks = (s >> 9) & 7;
      int mt = (s >> 12) & 3; int c = s >> 14;
      int tap = mt * 16 + (lane & 15);
      int k = ks * 32 + (lane >> 4) * 8 + j;
      float v = (tap < 49) ? w_f2[(c * 49 + tap) * 256 + k] : 0.f;
      w2b[s] = f2bf(v);
    } else if (i < A2) {
      int s = i - A1;
      int k = s & 31; int n = (s >> 5) & 63; int u = s >> 11;
      int t = u % 9; int v = u / 9; int kc = v & 1; int ocg = v >> 1;
      te2b[s] = f2bf(w_te2[((ocg * 64 + n) * 64 + kc * 32 + k) * 9 + t]);
    } else if (i < A3) {
      int s = i - A2;
      int k = s & 31; int n = (s >> 5) & 63; int u = s >> 11;
      int t = u % 9; int kc = u / 9;
      g1b[s] = f2bf(w_g1[(n * 128 + kc * 32 + k) * 9 + t]);
    } else if (i < A4) {
      int s = i - A3;
      int k = s & 31; int n = (s >> 5) & 63; int u = s >> 11;
      int t = u % 9; int v = u / 9; int kc = v & 3; int ocg = v >> 2;
      f1b[s] = f2bf(w_f1[((ocg * 64 + n) * 256 + kc * 32 + k) * 9 + t]);
    } else {
      int s = i - A4;
      wsf[O_WG2 + s] = w_g2[s];
    }
  }
  // SS: 16 slots per (b,o); slot s sums i in [s*8, s*8+8); shfl-reduce across slots.
  if (gid < 16384) {
    const int g = gid >> 4, slot = gid & 15;
    const int b = g >> 8, o = g & 255;
    const int lab = labels[b];
    float St[9];
#pragma unroll
    for (int t = 0; t < 9; ++t) St[t] = 0.f;
#pragma unroll 2
    for (int k = 0; k < 8; ++k) {
      const int i = slot * 8 + k;
      const float e = emb[lab * 128 + i];
      const float* wr = w_f1 + (size_t)(o * 256 + 128 + i) * 9;
#pragma unroll
      for (int t = 0; t < 9; ++t) St[t] += wr[t] * e;
    }
#pragma unroll
    for (int d = 1; d < 16; d <<= 1)
#pragma unroll
      for (int t = 0; t < 9; ++t) St[t] += __shfl_xor(St[t], d, 64);
    if (slot == 0) {
#pragma unroll
      for (int ch = 0; ch < 3; ++ch)
#pragma unroll
        for (int cw = 0; cw < 3; ++cw) {
          float sum = 0.f;
#pragma unroll
          for (int t = 0; t < 9; ++t) {
            int kh = t / 3, kw = t - kh * 3;
            bool ok = !(ch == 0 && kh == 0) && !(ch == 2 && kh == 2) &&
                      !(cw == 0 && kw == 0) && !(cw == 2 && kw == 2);
            if (ok) sum += St[t];
          }
          wsf[O_SS + g * 9 + ch * 3 + cw] = sum;
        }
    }
  }
}

// ---------------- small VALU 3x3 conv (te1 only: ICH=3) ----------------
template<typename TIn, int ICH, bool PIXMAJOR>
__global__ __launch_bounds__(256, 2) void conv3x3_kernel(
    const TIn* __restrict__ in, const float* __restrict__ wf,
    const float* __restrict__ bias,
    __hip_bfloat16* __restrict__ out, const int och_total)
{
  constexpr int CH = (ICH < 16) ? ICH : 16;
  constexpr int NCHUNK = ICH / CH;
  __shared__ TIn sIn[CH][18][20];
  const int tid = threadIdx.x;
  const int b = blockIdx.z;
  const int ob = blockIdx.y;
  const int och0 = ob * 32;
  const int tileY = blockIdx.x >> 3, tileX = blockIdx.x & 7;
  const int ty = tid >> 4, tx = tid & 15;
  const int h = tileY * 16 + ty, w = tileX * 16 + tx;
  const int h0 = tileY * 16 - 1, w0 = tileX * 16 - 1;

  float acc[32];
#pragma unroll
  for (int o = 0; o < 32; ++o) acc[o] = bias[och0 + o];

  for (int cc = 0; cc < NCHUNK; ++cc) {
    if (cc) __syncthreads();
    for (int e = tid; e < CH * 324; e += 256) {
      int ic = e / 324, r = e - ic * 324;
      int y = r / 18, x = r - y * 18;
      int gh = h0 + y, gw = w0 + x;
      TIn v = TIn(0.f);
      if ((unsigned)gh < 128u && (unsigned)gw < 128u)
        v = in[((b * ICH + cc * CH + ic) << 14) + (gh << 7) + gw];
      sIn[ic][y][x] = v;
    }
    __syncthreads();
#pragma unroll 1
    for (int ic = 0; ic < CH; ++ic) {
      const float* wrow = wf + (ob * ICH + cc * CH + ic) * 288;  // [9][32]
#pragma unroll
      for (int t = 0; t < 9; ++t) {
        const int kh = t / 3, kw = t - kh * 3;
        const float v = loadf(sIn[ic][ty + kh][tx + kw]);
#pragma unroll
        for (int o = 0; o < 32; ++o)
          acc[o] = fmaf(wrow[t * 32 + o], v, acc[o]);
      }
    }
  }

  const int pix = (h << 7) + w;
  if constexpr (!PIXMAJOR) {
#pragma unroll
    for (int o = 0; o < 32; ++o)
      out[((b * och_total + och0 + o) << 14) + pix] = f2bf(fmaxf(acc[o], 0.f));
  } else {
    union { uint4 u4[4]; __hip_bfloat16 hh[32]; } pk;
#pragma unroll
    for (int o = 0; o < 32; ++o) pk.hh[o] = f2bf(fmaxf(acc[o], 0.f));
    uint4* dst = reinterpret_cast<uint4*>(out + ((size_t)(b << 14) + pix) * och_total + och0);
#pragma unroll
    for (int i = 0; i < 4; ++i) dst[i] = pk.u4[i];
  }
}

// ---------------- MFMA implicit-GEMM 3x3 conv (zero pad), pixel-major bf16 ----------------
template<int ICH, bool ADD_SS, bool GATE>
__global__ __launch_bounds__(256, 2) void conv3x3_mfma_kernel(
    const __hip_bfloat16* __restrict__ in, const __hip_bfloat16* __restrict__ wb,
    const float* __restrict__ bias, const float* __restrict__ SS,
    __hip_bfloat16* __restrict__ out, const int och_total,
    const float* __restrict__ wg2, const float* __restrict__ b_g2,
    const int* __restrict__ labels, const float* __restrict__ ci,
    float* __restrict__ out_cg, float* __restrict__ out_cond,
    float* __restrict__ inten)
{
  constexpr int NKC = ICH / 32;
  __shared__ __hip_bfloat16 smem[36000];   // sH 324*40 | sW 9*64*40  (72 KB)
#define SHX(pos, k) smem[(pos) * 40 + (k)]
#define SWX(t, n, k) smem[12960 + (((t) * 64 + (n)) * 40) + (k)]
  const int tid = threadIdx.x, b = blockIdx.z, ocg = blockIdx.y;
  const int tileY = blockIdx.x >> 3, tileX = blockIdx.x & 7;
  const int h0 = tileY * 16 - 1, w0 = tileX * 16 - 1;
  const int wave = tid >> 6, lane = tid & 63, m16 = lane & 15, quad = lane >> 4;

  f32x4 acc[4][4];
#pragma unroll
  for (int i = 0; i < 4; ++i)
#pragma unroll
    for (int j = 0; j < 4; ++j) acc[i][j] = f32x4{0.f, 0.f, 0.f, 0.f};

  for (int kc = 0; kc < NKC; ++kc) {
    if (kc) __syncthreads();
    for (int e = tid; e < 1296; e += 256) {
      int pos = e >> 2, q = e & 3;
      int y = pos / 18, x = pos - y * 18;
      int gh = h0 + y, gw = w0 + x;
      uint4 v = uint4{0u, 0u, 0u, 0u};
      if ((unsigned)gh < 128u && (unsigned)gw < 128u)
        v = *(const uint4*)(in + ((size_t)((b << 14) + (gh << 7) + gw)) * ICH + kc * 32 + q * 8);
      *(uint4*)&SHX(pos, q * 8) = v;
    }
    const uint4* wsrc = (const uint4*)(wb + ((size_t)(ocg * NKC + kc)) * 9 * 64 * 32);
    for (int e = tid; e < 2304; e += 256) {
      int q = e & 3, n = (e >> 2) & 63, t = e >> 8;
      *(uint4*)&SWX(t, n, q * 8) = wsrc[e];
    }
    __syncthreads();
#pragma unroll
    for (int t = 0; t < 9; ++t) {
      const int dy = t / 3, dx = t - dy * 3;
      bf16x8 bfr[4];
#pragma unroll
      for (int nt = 0; nt < 4; ++nt)
        bfr[nt] = *(const bf16x8*)&SWX(t, nt * 16 + m16, quad * 8);
#pragma unroll
      for (int mi = 0; mi < 4; ++mi) {
        const int py = wave * 4 + mi;
        const bf16x8 afr = *(const bf16x8*)&SHX((py + dy) * 18 + dx + m16, quad * 8);
#pragma unroll
        for (int nt = 0; nt < 4; ++nt)
          acc[mi][nt] = __builtin_amdgcn_mfma_f32_16x16x32_bf16(afr, bfr[nt], acc[mi][nt], 0, 0, 0);
      }
    }
  }

  float bv[4];
#pragma unroll
  for (int nt = 0; nt < 4; ++nt) bv[nt] = bias[ocg * 64 + nt * 16 + m16];

  if constexpr (GATE) {
    __syncthreads();   // all MFMA smem reads done
    __hip_bfloat16* sG = smem;
#pragma unroll
    for (int mi = 0; mi < 4; ++mi)
#pragma unroll
      for (int nt = 0; nt < 4; ++nt) {
        const int och = nt * 16 + m16;
#pragma unroll
        for (int r = 0; r < 4; ++r) {
          const int p = (wave * 4 + mi) * 16 + quad * 4 + r;
          sG[p * 68 + och] = f2bf(fmaxf(acc[mi][nt][r] + bv[nt], 0.f));
        }
      }
    __syncthreads();
    const int p = tid;
    float a6[6];
#pragma unroll
    for (int k = 0; k < 6; ++k) a6[k] = b_g2[k];
#pragma unroll
    for (int i8 = 0; i8 < 8; ++i8) {
      const bf16x8 v8 = *(const bf16x8*)&sG[p * 68 + i8 * 8];
#pragma unroll
      for (int j = 0; j < 8; ++j) {
        const float v = bf2f(((const __hip_bfloat16*)&v8)[j]);
#pragma unroll
        for (int k = 0; k < 6; ++k)
          a6[k] = fmaf(wg2[k * 64 + i8 * 8 + j], v, a6[k]);
      }
    }
    const int lab = labels[b];
    float gate[6], gl = 0.f;
#pragma unroll
    for (int k = 0; k < 6; ++k) {
      gate[k] = 1.f / (1.f + __expf(-a6[k]));
      gl = (k == lab) ? gate[k] : gl;
    }
    const float civ = ci[lab];
    const float it = gl * civ;
    const int h = tileY * 16 + (p >> 4), w = tileX * 16 + (p & 15);
    const int pix = (h << 7) + w;
#pragma unroll
    for (int k = 0; k < 6; ++k)
      out_cg[((b * 6 + k) << 14) + pix] = (k == lab) ? gate[k] : 0.f;
    inten[(b << 14) + pix] = it;
    out_cond[(b << 14) + pix] = it * gl;
    return;
  }

#pragma unroll
  for (int mi = 0; mi < 4; ++mi) {
    const int py = wave * 4 + mi;
    const int h = tileY * 16 + py;
    const int chc = (h == 0) ? 0 : ((h == 127) ? 2 : 1);
#pragma unroll
    for (int nt = 0; nt < 4; ++nt) {
      float sr0 = 0.f, sr1 = 0.f, sr2 = 0.f;
      if constexpr (ADD_SS) {
        const float* sp = SS + ((size_t)(b << 8) + (ocg * 64 + nt * 16 + m16)) * 9;
        sr0 = sp[chc * 3 + 0]; sr1 = sp[chc * 3 + 1]; sr2 = sp[chc * 3 + 2];
      }
      const int och = ocg * 64 + nt * 16 + m16;
#pragma unroll
      for (int r = 0; r < 4; ++r) {
        const int px = quad * 4 + r;
        const int w = tileX * 16 + px;
        float v = acc[mi][nt][r] + bv[nt];
        if constexpr (ADD_SS)
          v += (w == 0) ? sr0 : ((w == 127) ? sr2 : sr1);
        v = fmaxf(v, 0.f);
        out[((size_t)((b << 14) + (h << 7) + w)) * och_total + och] = f2bf(v);
      }
    }
  }
#undef SHX
#undef SWX
}

// ---------------- fused GEMM+softmax v16: v12 (proven 91 us) + fused diff step 1 ----
// R23: cooperative diff is dead in this harness (v14/v15 both failed identically
// regardless of fencing) -> reverted. This round re-adds ONLY the v9-proven
// (absmax-passing) diff-1 fusion to the proven v12 gemm: after a channel's softmax
// weights land in sT, stage a 7x134 edge-clamped depth halo and do the 49-tap
// stencil via tap-parity thread pairs + shfl_xor(1). Deletes one diff dispatch
// AND its 154 MB weight HBM re-read. v9's regression was the register A-loads
// (proven by v13's repeat), not this epilogue.
__global__ __launch_bounds__(256, 3) void gemm_softmax_kernel(
    const __hip_bfloat16* __restrict__ f1, const __hip_bfloat16* __restrict__ w2b,
    const float* __restrict__ b_f2, const float* __restrict__ inten,
    __hip_bfloat16* __restrict__ wout,
    const float* __restrict__ depth, float* __restrict__ lat1)
{
  __shared__ __hip_bfloat16 sW[2][8192];       // 2 x 16 KB: [mtl2][ks8][lane64][8]
  __shared__ __hip_bfloat16 sT[49][136];       // softmax out: [tap][pix] (+8 pad)
  __shared__ float sL[7][136];                 // depth halo rows for fused diff1
  const int tid = threadIdx.x;
  const int pix0 = blockIdx.x * 128;           // one (b,row): 128 px
  const int c0 = blockIdx.y * 8;                 // 8 channels per block
  const int wave = tid >> 6, lane = tid & 63;
  const int n16 = lane & 15, quad = lane >> 4;
  const int p0 = pix0 + wave * 16 + n16;         // pixel group 0
  const int p1 = p0 + 64;                        // pixel group 1

  bf16x8 bfr0[8], bfr1[8];
#pragma unroll
  for (int ks = 0; ks < 8; ++ks) {
    bfr0[ks] = *(const bf16x8*)(f1 + (size_t)p0 * 256 + ks * 32 + quad * 8);
    bfr1[ks] = *(const bf16x8*)(f1 + (size_t)p1 * 256 + ks * 32 + quad * 8);
  }

  const float s0v = inten[p0], s1v = inten[p1];
  const int ob = pix0 >> 14, row = (pix0 >> 7) & 127;

#define W2U(u) ((const uint4*)(w2b + ((((size_t)c0 + ((u) >> 1)) * 4 + (((u) & 1) << 1)) << 12)))

  {
    const uint4* s0 = W2U(0);
    uint4* d0 = (uint4*)&sW[0][0];
#pragma unroll
    for (int j = 0; j < 4; ++j)
      gld_lds16(s0 + tid + j * 256, d0 + tid + j * 256);
  }
  __syncthreads();

#pragma unroll 1
  for (int cl = 0; cl < 8; ++cl) {
    const int c = c0 + cl;
    f32x4 ac0[4], ac1[4];
#pragma unroll
    for (int mt = 0; mt < 4; ++mt) { ac0[mt] = f32x4{0.f,0.f,0.f,0.f}; ac1[mt] = f32x4{0.f,0.f,0.f,0.f}; }

#pragma unroll
    for (int h = 0; h < 2; ++h) {
      const int u = cl * 2 + h;
      {
        const uint4* sn = W2U(u < 15 ? u + 1 : 15);
        uint4* dn = (uint4*)&sW[(u + 1) & 1][0];
#pragma unroll
        for (int j = 0; j < 4; ++j)
          gld_lds16(sn + tid + j * 256, dn + tid + j * 256);
      }

      const __hip_bfloat16* bufp = &sW[u & 1][0];
#pragma unroll
      for (int ks = 0; ks < 8; ++ks) {
        const bf16x8 a0 = *(const bf16x8*)(bufp + ((ks) * 64 + lane) * 8);
        const bf16x8 a1 = *(const bf16x8*)(bufp + ((8 + ks) * 64 + lane) * 8);
        ac0[h * 2 + 0] = __builtin_amdgcn_mfma_f32_16x16x32_bf16(a0, bfr0[ks], ac0[h * 2 + 0], 0, 0, 0);
        ac1[h * 2 + 0] = __builtin_amdgcn_mfma_f32_16x16x32_bf16(a0, bfr1[ks], ac1[h * 2 + 0], 0, 0, 0);
        ac0[h * 2 + 1] = __builtin_amdgcn_mfma_f32_16x16x32_bf16(a1, bfr0[ks], ac0[h * 2 + 1], 0, 0, 0);
        ac1[h * 2 + 1] = __builtin_amdgcn_mfma_f32_16x16x32_bf16(a1, bfr1[ks], ac1[h * 2 + 1], 0, 0, 0);
      }
      __syncthreads();   // drains DMA (vmcnt) + fences buffer swap
    }

    const float b48 = b_f2[c * 49 + 48];
#pragma unroll
    for (int g = 0; g < 2; ++g) {
      f32x4* ac = g ? ac1 : ac0;
      const float s = g ? s1v : s0v;
      float mx = -3.4e38f;
#pragma unroll
      for (int mt = 0; mt < 3; ++mt)
#pragma unroll
        for (int r = 0; r < 4; ++r) {
          const float lv = (ac[mt][r] + b_f2[c * 49 + mt * 16 + quad * 4 + r]) * s;
          ac[mt][r] = lv;
          mx = fmaxf(mx, lv);
        }
      const float v48 = (ac[3][0] + b48) * s;
      if (quad == 0) mx = fmaxf(mx, v48);
      mx = fmaxf(mx, __shfl_xor(mx, 16, 64));
      mx = fmaxf(mx, __shfl_xor(mx, 32, 64));
      float sum = 0.f;
#pragma unroll
      for (int mt = 0; mt < 3; ++mt)
#pragma unroll
        for (int r = 0; r < 4; ++r) {
          const float e = __expf(ac[mt][r] - mx);
          ac[mt][r] = e;
          sum += e;
        }
      const float e48 = (quad == 0) ? __expf(v48 - mx) : 0.f;
      sum += e48;
      sum += __shfl_xor(sum, 16, 64);
      sum += __shfl_xor(sum, 32, 64);
      const float rs = 1.f / sum;

      const int px = wave * 16 + n16 + g * 64;
#pragma unroll
      for (int mt = 0; mt < 3; ++mt)
#pragma unroll
        for (int r = 0; r < 4; ++r)
          sT[mt * 16 + quad * 4 + r][px] = f2bf(ac[mt][r] * rs);
      if (quad == 0) sT[48][px] = f2bf(e48 * rs);
    }
    __syncthreads();   // sT visible

    // contiguous store: one 12.25 KB block per (b,c,row) = 784 uint4
    __hip_bfloat16* wob = wout + ((size_t)((ob * 24 + c) * 128 + row)) * 6272;
    for (int e = tid; e < 784; e += 256) {
      const int tap = e >> 4, qq = e & 15;
      *(uint4*)(wob + tap * 128 + qq * 8) = *(const uint4*)&sT[tap][qq * 8];
    }

    // stage depth halo (edge-clamped) for fused diffusion step 1
    const float* dch = depth + (((size_t)(ob * 24 + c)) << 14);
    for (int e = tid; e < 938; e += 256) {       // 7 rows x 134 cols
      const int y = e / 134, x = e - y * 134;
      const int gh = min(max(row - 3 + y, 0), 127);
      const int gw = min(max(x - 3, 0), 127);
      sL[y][x] = dch[(gh << 7) + gw];
    }
    __syncthreads();   // sL visible (sT also fully stored before reuse below)

    // fused diff step 1: thread pair (w = tid>>1) splits taps by parity
    {
      const int w = tid >> 1, par = tid & 1;
      float a = 0.f;
#pragma unroll
      for (int i = 0; i < 25; ++i) {
        const int t = par + 2 * i;
        if (t < 49) {
          const int kh = t / 7, kw = t - kh * 7;
          a = fmaf(bf2f(sT[t][w]), sL[kh][w + kw], a);
        }
      }
      a += __shfl_xor(a, 1, 64);
      if (!par) lat1[(((size_t)(ob * 24 + c)) << 14) + (row << 7) + w] = a;
    }
    __syncthreads();   // WAR: sT/sL reused by next channel
  }
#undef W2U
}

// ---------------- diffusion step v5: row-major weights (proven) ----------
__global__ __launch_bounds__(256) void diff_kernel(
    const float* __restrict__ lin, const __hip_bfloat16* __restrict__ wts,
    float* __restrict__ lout)
{
  __shared__ float sT[22][136];   // 16+6 rows, 128+6 cols (136: row 16B-aligned)
  const int bc = blockIdx.y;
  const int h0 = blockIdx.x * 16;
  const int tid = threadIdx.x;
  for (int e = tid; e < 22 * 134; e += 256) {
    int y = e / 134, x = e - y * 134;
    int gh = min(max(h0 - 3 + y, 0), 127), gw = min(max(x - 3, 0), 127);
    sT[y][x] = lin[(bc << 14) + (gh << 7) + gw];
  }
  __syncthreads();
  const int tx8 = (tid & 15) * 8;  // first of 8 pixels in w
  const int ty = tid >> 4;         // row 0..15
  const int h = h0 + ty;
  const __hip_bfloat16* wp = wts + ((size_t)(bc * 128 + h)) * 6272 + tx8;
  float a[8];
#pragma unroll
  for (int j = 0; j < 8; ++j) a[j] = 0.f;
#pragma unroll
  for (int kh = 0; kh < 7; ++kh) {
    const float* row = &sT[ty + kh][tx8];
    float r[16];
    *(f32x4*)&r[0]  = *(const f32x4*)(row);
    *(f32x4*)&r[4]  = *(const f32x4*)(row + 4);
    *(f32x4*)&r[8]  = *(const f32x4*)(row + 8);
    *(f32x4*)&r[12] = *(const f32x4*)(row + 12);
#pragma unroll
    for (int kw = 0; kw < 7; ++kw) {
      const int t = kh * 7 + kw;
      const uint4 wq = *(const uint4*)(wp + t * 128);
      a[0] = fmaf(bflo(wq.x), r[kw + 0], a[0]);
      a[1] = fmaf(bfhi(wq.x), r[kw + 1], a[1]);
      a[2] = fmaf(bflo(wq.y), r[kw + 2], a[2]);
      a[3] = fmaf(bfhi(wq.y), r[kw + 3], a[3]);
      a[4] = fmaf(bflo(wq.z), r[kw + 4], a[4]);
      a[5] = fmaf(bfhi(wq.z), r[kw + 5], a[5]);
      a[6] = fmaf(bflo(wq.w), r[kw + 6], a[6]);
      a[7] = fmaf(bfhi(wq.w), r[kw + 7], a[7]);
    }
  }
  float* dst = lout + (bc << 14) + (h << 7) + tx8;
  *(f32x4*)dst       = f32x4{a[0], a[1], a[2], a[3]};
  *(f32x4*)(dst + 4) = f32x4{a[4], a[5], a[6], a[7]};
}

// ---------------- orchestration ----------------
extern "C" void kernel_launch(void* const* d_in, const int* in_sizes, int n_in,
                              void* d_out, int out_size, void* d_ws, size_t ws_size,
                              hipStream_t stream)
{
  const float* depth = (const float*)d_in[0];
  const float* texf  = (const float*)d_in[1];
  const int*   labels= (const int*)d_in[2];
  const float* w_te1 = (const float*)d_in[3];
  const float* b_te1 = (const float*)d_in[4];
  const float* w_te2 = (const float*)d_in[5];
  const float* b_te2 = (const float*)d_in[6];
  const float* emb   = (const float*)d_in[7];
  const float* w_f1  = (const float*)d_in[8];
  const float* b_f1  = (const float*)d_in[9];
  const float* w_f2  = (const float*)d_in[10];
  const float* b_f2  = (const float*)d_in[11];
  const float* w_g1  = (const float*)d_in[12];
  const float* b_g1  = (const float*)d_in[13];
  const float* w_g2  = (const float*)d_in[14];
  const float* b_g2  = (const float*)d_in[15];
  const float* ci    = (const float*)d_in[16];

  char*  ws  = (char*)d_ws;
  float* wsf = (float*)d_ws;
  __hip_bfloat16* w2bf  = (__hip_bfloat16*)(ws + BO_W2B);
  __hip_bfloat16* te2bf = (__hip_bfloat16*)(ws + BO_TE2B);
  __hip_bfloat16* g1bf  = (__hip_bfloat16*)(ws + BO_WG1B);
  __hip_bfloat16* f1bf  = (__hip_bfloat16*)(ws + BO_WF1B);
  __hip_bfloat16* tex   = (__hip_bfloat16*)(ws + BO_TEX);
  __hip_bfloat16* f1    = (__hip_bfloat16*)(ws + BO_F1);
  float* ping           = (float*)(ws + BO_PING);
  float* pong           = (float*)(ws + BO_PONG);
  __hip_bfloat16* wts   = (__hip_bfloat16*)(ws + BO_W);
  __hip_bfloat16* t1    = (__hip_bfloat16*)(ws + BO_T1);

  float* out      = (float*)d_out;
  float* out_enh  = out;                 // [4][24][128][128]
  float* out_cg   = out + 1572864;       // [4][6][128][128]
  float* out_cond = out + 1966080;       // [4][1][128][128]

  prep_kernel<<<512, 256, 0, stream>>>(w_te1, w_te2, w_g1, w_f1, w_f2, w_g2, emb, labels, wsf);
  conv3x3_kernel<float, 3, true><<<dim3(64, 2, 4), 256, 0, stream>>>(texf, wsf + O_WTE1, b_te1, t1, 64);
  conv3x3_mfma_kernel<64,  false, false><<<dim3(64, 2, 4), 256, 0, stream>>>(
      t1, te2bf, b_te2, nullptr, tex, 128,
      nullptr, nullptr, nullptr, nullptr, nullptr, nullptr, nullptr);
  // gate1 conv + fused gate2
  conv3x3_mfma_kernel<128, false, true><<<dim3(64, 1, 4), 256, 0, stream>>>(
      tex, g1bf, b_g1, nullptr, nullptr, 64,
      wsf + O_WG2, b_g2, labels, ci, out_cg, out_cond, wsf + O_INT);
  conv3x3_mfma_kernel<128, true, false><<<dim3(64, 4, 4), 256, 0, stream>>>(
      tex, f1bf, b_f1, wsf + O_SS, f1, 256,
      nullptr, nullptr, nullptr, nullptr, nullptr, nullptr, nullptr);
  // GEMM + softmax + fused diffusion step 1 (writes wts AND ping)
  gemm_softmax_kernel<<<dim3(512, 3), 256, 0, stream>>>(f1, w2bf, b_f2, wsf + O_INT, wts, depth, ping);

  // remaining 7 diffusion steps
  dim3 dgrid(8, 96);
  diff_kernel<<<dgrid, 256, 0, stream>>>(ping, wts, pong);
  diff_kernel<<<dgrid, 256, 0, stream>>>(pong, wts, ping);
  diff_kernel<<<dgrid, 256, 0, stream>>>(ping, wts, pong);
  diff_kernel<<<dgrid, 256, 0, stream>>>(pong, wts, ping);
  diff_kernel<<<dgrid, 256, 0, stream>>>(ping, wts, pong);
  diff_kernel<<<dgrid, 256, 0, stream>>>(pong, wts, ping);
  diff_kernel<<<dgrid, 256, 0, stream>>>(ping, wts, out_enh);
}

// Round 10
// 487.130 us; speedup vs baseline: 1.3559x; 1.0122x over previous
//
#include <hip/hip_runtime.h>
#include <hip/hip_bf16.h>
#include <stdint.h>

#define DINL __device__ __forceinline__

DINL float bf2f(__hip_bfloat16 v) { return __bfloat162float(v); }
DINL __hip_bfloat16 f2bf(float v) { return __float2bfloat16(v); }
DINL float bflo(unsigned int u) { return __uint_as_float(u << 16); }
DINL float bfhi(unsigned int u) { return __uint_as_float(u & 0xffff0000u); }

DINL float loadf(float v) { return v; }
DINL float loadf(__hip_bfloat16 v) { return __bfloat162float(v); }

typedef __attribute__((ext_vector_type(8))) short bf16x8;
typedef __attribute__((ext_vector_type(4))) float f32x4;

// async global->LDS DMA, 16 B per lane. LDS dest must be wave-uniform base + lane*16
// (true for all call sites: addresses are base + tid*16 + const).
DINL void gld_lds16(const void* g, void* l) {
  __builtin_amdgcn_global_load_lds(
      (const __attribute__((address_space(1))) unsigned int*)g,
      (__attribute__((address_space(3))) unsigned int*)l, 16, 0, 0);
}

// ---------------- ws layout ----------------
// fp32 region (float offsets):
#define O_WTE1 0         // [2][3][9][32] fp32 blocked (te1 VALU conv)   1728
#define O_WG2  1792      // [6][64]                                      384
#define O_SS   2304      // [4][256][9]  border-class emb sums           9216
#define O_INT  11520     // [4][16384] intensity                         65536
// fp32 region ends at float 77056 = byte 308224
// bf16/byte offsets:
#define BO_W2B   308224u   // w_f2 bf16 MFMA *A-fragment* layout [24][4][8][64][8]  786432 B
#define BO_TE2B 1094656u   // w_te2 bf16 [2][2][9][64][32]      147456 B
#define BO_WG1B 1242112u   // w_g1  bf16 [1][4][9][64][32]      147456 B
#define BO_WF1B 1389568u   // w_f1  bf16 [4][4][9][64][32]      589824 B (ends 1979392)
#define BO_TEX  4194304u   // tex bf16 pixel-major [4][16384][128]  16.78 MB
#define BO_F1   20971520u  // f1  bf16 pixel-major [4][16384][256]  33.55 MB
#define BO_PING 54525952u  // fp32 [4*24*16384]  6.29 MB
#define BO_PONG 60817408u
#define BO_W    67108864u  // weights bf16 ROW-MAJOR [4][24][128 row][49 tap][128 w]  154.14 MB
#define BO_T1   BO_W             // t1 bf16 pixel-major [4][16384][64] (dead before W written)

// ---------------- prep: weight re-layouts (bf16 MFMA blocks) + SS table ----------------
__global__ __launch_bounds__(256) void prep_kernel(
    const float* __restrict__ w_te1, const float* __restrict__ w_te2,
    const float* __restrict__ w_g1,  const float* __restrict__ w_f1,
    const float* __restrict__ w_f2,  const float* __restrict__ w_g2,
    const float* __restrict__ emb,   const int* __restrict__ labels,
    float* __restrict__ wsf)
{
  const int gid = blockIdx.x * 256 + threadIdx.x;
  const int stride = gridDim.x * 256;
  const int A0 = 1728, A1 = A0 + 393216, A2 = A1 + 73728, A3 = A2 + 73728,
            A4 = A3 + 294912, A5 = A4 + 384;
  __hip_bfloat16* w2b  = (__hip_bfloat16*)((char*)wsf + BO_W2B);
  __hip_bfloat16* te2b = (__hip_bfloat16*)((char*)wsf + BO_TE2B);
  __hip_bfloat16* g1b  = (__hip_bfloat16*)((char*)wsf + BO_WG1B);
  __hip_bfloat16* f1b  = (__hip_bfloat16*)((char*)wsf + BO_WF1B);
  for (int i = gid; i < A5; i += stride) {
    if (i < A0) {
      int s = i; int o = s / 27; int r = s - o * 27; int ic = r / 9; int t = r - ic * 9;
      wsf[O_WTE1 + (((o >> 5) * 3 + ic) * 9 + t) * 32 + (o & 31)] = w_te1[s];
    } else if (i < A1) {
      // w_f2 [1176][256] fp32 -> bf16 A-fragment layout [c24][mt4][ks8][lane64][8]
      int s = i - A0;
      int j = s & 7; int lane = (s >> 3) & 63; int ks = (s >> 9) & 7;
      int mt = (s >> 12) & 3; int c = s >> 14;
      int tap = mt * 16 + (lane & 15);
      int k = ks * 32 + (lane >> 4) * 8 + j;
      float v = (tap < 49) ? w_f2[(c * 49 + tap) * 256 + k] : 0.f;
      w2b[s] = f2bf(v);
    } else if (i < A2) {
      int s = i - A1;
      int k = s & 31; int n = (s >> 5) & 63; int u = s >> 11;
      int t = u % 9; int v = u / 9; int kc = v & 1; int ocg = v >> 1;
      te2b[s] = f2bf(w_te2[((ocg * 64 + n) * 64 + kc * 32 + k) * 9 + t]);
    } else if (i < A3) {
      int s = i - A2;
      int k = s & 31; int n = (s >> 5) & 63; int u = s >> 11;
      int t = u % 9; int kc = u / 9;
      g1b[s] = f2bf(w_g1[(n * 128 + kc * 32 + k) * 9 + t]);
    } else if (i < A4) {
      int s = i - A3;
      int k = s & 31; int n = (s >> 5) & 63; int u = s >> 11;
      int t = u % 9; int v = u / 9; int kc = v & 3; int ocg = v >> 2;
      f1b[s] = f2bf(w_f1[((ocg * 64 + n) * 256 + kc * 32 + k) * 9 + t]);
    } else {
      int s = i - A4;
      wsf[O_WG2 + s] = w_g2[s];
    }
  }
  // SS: 16 slots per (b,o); slot s sums i in [s*8, s*8+8); shfl-reduce across slots.
  if (gid < 16384) {
    const int g = gid >> 4, slot = gid & 15;
    const int b = g >> 8, o = g & 255;
    const int lab = labels[b];
    float St[9];
#pragma unroll
    for (int t = 0; t < 9; ++t) St[t] = 0.f;
#pragma unroll 2
    for (int k = 0; k < 8; ++k) {
      const int i = slot * 8 + k;
      const float e = emb[lab * 128 + i];
      const float* wr = w_f1 + (size_t)(o * 256 + 128 + i) * 9;
#pragma unroll
      for (int t = 0; t < 9; ++t) St[t] += wr[t] * e;
    }
#pragma unroll
    for (int d = 1; d < 16; d <<= 1)
#pragma unroll
      for (int t = 0; t < 9; ++t) St[t] += __shfl_xor(St[t], d, 64);
    if (slot == 0) {
#pragma unroll
      for (int ch = 0; ch < 3; ++ch)
#pragma unroll
        for (int cw = 0; cw < 3; ++cw) {
          float sum = 0.f;
#pragma unroll
          for (int t = 0; t < 9; ++t) {
            int kh = t / 3, kw = t - kh * 3;
            bool ok = !(ch == 0 && kh == 0) && !(ch == 2 && kh == 2) &&
                      !(cw == 0 && kw == 0) && !(cw == 2 && kw == 2);
            if (ok) sum += St[t];
          }
          wsf[O_SS + g * 9 + ch * 3 + cw] = sum;
        }
    }
  }
}

// ---------------- small VALU 3x3 conv (te1 only: ICH=3) ----------------
template<typename TIn, int ICH, bool PIXMAJOR>
__global__ __launch_bounds__(256, 2) void conv3x3_kernel(
    const TIn* __restrict__ in, const float* __restrict__ wf,
    const float* __restrict__ bias,
    __hip_bfloat16* __restrict__ out, const int och_total)
{
  constexpr int CH = (ICH < 16) ? ICH : 16;
  constexpr int NCHUNK = ICH / CH;
  __shared__ TIn sIn[CH][18][20];
  const int tid = threadIdx.x;
  const int b = blockIdx.z;
  const int ob = blockIdx.y;
  const int och0 = ob * 32;
  const int tileY = blockIdx.x >> 3, tileX = blockIdx.x & 7;
  const int ty = tid >> 4, tx = tid & 15;
  const int h = tileY * 16 + ty, w = tileX * 16 + tx;
  const int h0 = tileY * 16 - 1, w0 = tileX * 16 - 1;

  float acc[32];
#pragma unroll
  for (int o = 0; o < 32; ++o) acc[o] = bias[och0 + o];

  for (int cc = 0; cc < NCHUNK; ++cc) {
    if (cc) __syncthreads();
    for (int e = tid; e < CH * 324; e += 256) {
      int ic = e / 324, r = e - ic * 324;
      int y = r / 18, x = r - y * 18;
      int gh = h0 + y, gw = w0 + x;
      TIn v = TIn(0.f);
      if ((unsigned)gh < 128u && (unsigned)gw < 128u)
        v = in[((b * ICH + cc * CH + ic) << 14) + (gh << 7) + gw];
      sIn[ic][y][x] = v;
    }
    __syncthreads();
#pragma unroll 1
    for (int ic = 0; ic < CH; ++ic) {
      const float* wrow = wf + (ob * ICH + cc * CH + ic) * 288;  // [9][32]
#pragma unroll
      for (int t = 0; t < 9; ++t) {
        const int kh = t / 3, kw = t - kh * 3;
        const float v = loadf(sIn[ic][ty + kh][tx + kw]);
#pragma unroll
        for (int o = 0; o < 32; ++o)
          acc[o] = fmaf(wrow[t * 32 + o], v, acc[o]);
      }
    }
  }

  const int pix = (h << 7) + w;
  if constexpr (!PIXMAJOR) {
#pragma unroll
    for (int o = 0; o < 32; ++o)
      out[((b * och_total + och0 + o) << 14) + pix] = f2bf(fmaxf(acc[o], 0.f));
  } else {
    union { uint4 u4[4]; __hip_bfloat16 hh[32]; } pk;
#pragma unroll
    for (int o = 0; o < 32; ++o) pk.hh[o] = f2bf(fmaxf(acc[o], 0.f));
    uint4* dst = reinterpret_cast<uint4*>(out + ((size_t)(b << 14) + pix) * och_total + och0);
#pragma unroll
    for (int i = 0; i < 4; ++i) dst[i] = pk.u4[i];
  }
}

// ---------------- MFMA implicit-GEMM 3x3 conv (zero pad), pixel-major bf16 ----------------
template<int ICH, bool ADD_SS, bool GATE>
__global__ __launch_bounds__(256, 2) void conv3x3_mfma_kernel(
    const __hip_bfloat16* __restrict__ in, const __hip_bfloat16* __restrict__ wb,
    const float* __restrict__ bias, const float* __restrict__ SS,
    __hip_bfloat16* __restrict__ out, const int och_total,
    const float* __restrict__ wg2, const float* __restrict__ b_g2,
    const int* __restrict__ labels, const float* __restrict__ ci,
    float* __restrict__ out_cg, float* __restrict__ out_cond,
    float* __restrict__ inten)
{
  constexpr int NKC = ICH / 32;
  __shared__ __hip_bfloat16 smem[36000];   // sH 324*40 | sW 9*64*40  (72 KB)
#define SHX(pos, k) smem[(pos) * 40 + (k)]
#define SWX(t, n, k) smem[12960 + (((t) * 64 + (n)) * 40) + (k)]
  const int tid = threadIdx.x, b = blockIdx.z, ocg = blockIdx.y;
  const int tileY = blockIdx.x >> 3, tileX = blockIdx.x & 7;
  const int h0 = tileY * 16 - 1, w0 = tileX * 16 - 1;
  const int wave = tid >> 6, lane = tid & 63, m16 = lane & 15, quad = lane >> 4;

  f32x4 acc[4][4];
#pragma unroll
  for (int i = 0; i < 4; ++i)
#pragma unroll
    for (int j = 0; j < 4; ++j) acc[i][j] = f32x4{0.f, 0.f, 0.f, 0.f};

  for (int kc = 0; kc < NKC; ++kc) {
    if (kc) __syncthreads();
    for (int e = tid; e < 1296; e += 256) {
      int pos = e >> 2, q = e & 3;
      int y = pos / 18, x = pos - y * 18;
      int gh = h0 + y, gw = w0 + x;
      uint4 v = uint4{0u, 0u, 0u, 0u};
      if ((unsigned)gh < 128u && (unsigned)gw < 128u)
        v = *(const uint4*)(in + ((size_t)((b << 14) + (gh << 7) + gw)) * ICH + kc * 32 + q * 8);
      *(uint4*)&SHX(pos, q * 8) = v;
    }
    const uint4* wsrc = (const uint4*)(wb + ((size_t)(ocg * NKC + kc)) * 9 * 64 * 32);
    for (int e = tid; e < 2304; e += 256) {
      int q = e & 3, n = (e >> 2) & 63, t = e >> 8;
      *(uint4*)&SWX(t, n, q * 8) = wsrc[e];
    }
    __syncthreads();
#pragma unroll
    for (int t = 0; t < 9; ++t) {
      const int dy = t / 3, dx = t - dy * 3;
      bf16x8 bfr[4];
#pragma unroll
      for (int nt = 0; nt < 4; ++nt)
        bfr[nt] = *(const bf16x8*)&SWX(t, nt * 16 + m16, quad * 8);
#pragma unroll
      for (int mi = 0; mi < 4; ++mi) {
        const int py = wave * 4 + mi;
        const bf16x8 afr = *(const bf16x8*)&SHX((py + dy) * 18 + dx + m16, quad * 8);
#pragma unroll
        for (int nt = 0; nt < 4; ++nt)
          acc[mi][nt] = __builtin_amdgcn_mfma_f32_16x16x32_bf16(afr, bfr[nt], acc[mi][nt], 0, 0, 0);
      }
    }
  }

  float bv[4];
#pragma unroll
  for (int nt = 0; nt < 4; ++nt) bv[nt] = bias[ocg * 64 + nt * 16 + m16];

  if constexpr (GATE) {
    __syncthreads();   // all MFMA smem reads done
    __hip_bfloat16* sG = smem;
#pragma unroll
    for (int mi = 0; mi < 4; ++mi)
#pragma unroll
      for (int nt = 0; nt < 4; ++nt) {
        const int och = nt * 16 + m16;
#pragma unroll
        for (int r = 0; r < 4; ++r) {
          const int p = (wave * 4 + mi) * 16 + quad * 4 + r;
          sG[p * 68 + och] = f2bf(fmaxf(acc[mi][nt][r] + bv[nt], 0.f));
        }
      }
    __syncthreads();
    const int p = tid;
    float a6[6];
#pragma unroll
    for (int k = 0; k < 6; ++k) a6[k] = b_g2[k];
#pragma unroll
    for (int i8 = 0; i8 < 8; ++i8) {
      const bf16x8 v8 = *(const bf16x8*)&sG[p * 68 + i8 * 8];
#pragma unroll
      for (int j = 0; j < 8; ++j) {
        const float v = bf2f(((const __hip_bfloat16*)&v8)[j]);
#pragma unroll
        for (int k = 0; k < 6; ++k)
          a6[k] = fmaf(wg2[k * 64 + i8 * 8 + j], v, a6[k]);
      }
    }
    const int lab = labels[b];
    float gate[6], gl = 0.f;
#pragma unroll
    for (int k = 0; k < 6; ++k) {
      gate[k] = 1.f / (1.f + __expf(-a6[k]));
      gl = (k == lab) ? gate[k] : gl;
    }
    const float civ = ci[lab];
    const float it = gl * civ;
    const int h = tileY * 16 + (p >> 4), w = tileX * 16 + (p & 15);
    const int pix = (h << 7) + w;
#pragma unroll
    for (int k = 0; k < 6; ++k)
      out_cg[((b * 6 + k) << 14) + pix] = (k == lab) ? gate[k] : 0.f;
    inten[(b << 14) + pix] = it;
    out_cond[(b << 14) + pix] = it * gl;
    return;
  }

#pragma unroll
  for (int mi = 0; mi < 4; ++mi) {
    const int py = wave * 4 + mi;
    const int h = tileY * 16 + py;
    const int chc = (h == 0) ? 0 : ((h == 127) ? 2 : 1);
#pragma unroll
    for (int nt = 0; nt < 4; ++nt) {
      float sr0 = 0.f, sr1 = 0.f, sr2 = 0.f;
      if constexpr (ADD_SS) {
        const float* sp = SS + ((size_t)(b << 8) + (ocg * 64 + nt * 16 + m16)) * 9;
        sr0 = sp[chc * 3 + 0]; sr1 = sp[chc * 3 + 1]; sr2 = sp[chc * 3 + 2];
      }
      const int och = ocg * 64 + nt * 16 + m16;
#pragma unroll
      for (int r = 0; r < 4; ++r) {
        const int px = quad * 4 + r;
        const int w = tileX * 16 + px;
        float v = acc[mi][nt][r] + bv[nt];
        if constexpr (ADD_SS)
          v += (w == 0) ? sr0 : ((w == 127) ? sr2 : sr1);
        v = fmaxf(v, 0.f);
        out[((size_t)((b << 14) + (h << 7) + w)) * och_total + och] = f2bf(v);
      }
    }
  }
#undef SHX
#undef SWX
}

// ---------------- fused GEMM+softmax v17: single sW buffer, (256,4) ----------
// R24: v16's fused diff-1 cost +31 us inside gemm (halo re-reads + bank conflicts
// + 2 barriers/channel) for a 39 us dispatch saving -> net neutral, reverted per
// pre-committed criterion. This round decouples v13's two bundled changes:
// v13's failure was ONLY the (256,5) VGPR cap 102 < ~130 needed (VGPR_Count 48,
// scratch FETCH 507 MB); its occupancy gain was real (43.9%) and its single-buffer
// schedule passed correctness. Kernel uses 72 VGPR -> (256,4) caps at 128: no
// spill, LDS 29.7 KB -> 4 blocks/CU (16 waves vs 12) to hide the barrier drains.
// Failure signature to watch: VGPR_Count collapsing to ~48 again = spill = revert.
__global__ __launch_bounds__(256, 4) void gemm_softmax_kernel(
    const __hip_bfloat16* __restrict__ f1, const __hip_bfloat16* __restrict__ w2b,
    const float* __restrict__ b_f2, const float* __restrict__ inten,
    __hip_bfloat16* __restrict__ wout)
{
  __shared__ __hip_bfloat16 sW[8192];          // 16 KB: [mtl2][ks8][lane64][8]
  __shared__ __hip_bfloat16 sT[49][136];       // softmax out: [tap][pix] (+8 pad)
  const int tid = threadIdx.x;
  const int pix0 = blockIdx.x * 128;           // one (b,row): 128 px
  const int c0 = blockIdx.y * 8;                 // 8 channels per block
  const int wave = tid >> 6, lane = tid & 63;
  const int n16 = lane & 15, quad = lane >> 4;
  const int p0 = pix0 + wave * 16 + n16;         // pixel group 0
  const int p1 = p0 + 64;                        // pixel group 1

  // B fragments (f1, channel-invariant): 2 pixel groups x 8 ks-steps (64 VGPR)
  bf16x8 bfr0[8], bfr1[8];
#pragma unroll
  for (int ks = 0; ks < 8; ++ks) {
    bfr0[ks] = *(const bf16x8*)(f1 + (size_t)p0 * 256 + ks * 32 + quad * 8);
    bfr1[ks] = *(const bf16x8*)(f1 + (size_t)p1 * 256 + ks * 32 + quad * 8);
  }

  const float s0v = inten[p0], s1v = inten[p1];
  const int ob = pix0 >> 14, row = (pix0 >> 7) & 127;

  // unit u (0..15) = channel c0+(u>>1), mt-pair (u&1): 16 KB at w2b + unit<<12 elems
#define W2U(u) ((const uint4*)(w2b + ((((size_t)c0 + ((u) >> 1)) * 4 + (((u) & 1) << 1)) << 12)))

  // prologue: DMA unit 0
  {
    const uint4* s0 = W2U(0);
    uint4* d0 = (uint4*)&sW[0];
#pragma unroll
    for (int j = 0; j < 4; ++j)
      gld_lds16(s0 + tid + j * 256, d0 + tid + j * 256);
  }
  __syncthreads();   // drain: buf holds unit 0

#pragma unroll 1
  for (int cl = 0; cl < 8; ++cl) {
    const int c = c0 + cl;
    f32x4 ac0[4], ac1[4];
#pragma unroll
    for (int mt = 0; mt < 4; ++mt) { ac0[mt] = f32x4{0.f,0.f,0.f,0.f}; ac1[mt] = f32x4{0.f,0.f,0.f,0.f}; }

#pragma unroll
    for (int h = 0; h < 2; ++h) {
      const int u = cl * 2 + h;
      // compute unit u (mt = 2h, 2h+1) from sW: 32 MFMA
#pragma unroll
      for (int ks = 0; ks < 8; ++ks) {
        const bf16x8 a0 = *(const bf16x8*)(&sW[0] + ((ks) * 64 + lane) * 8);
        const bf16x8 a1 = *(const bf16x8*)(&sW[0] + ((8 + ks) * 64 + lane) * 8);
        ac0[h * 2 + 0] = __builtin_amdgcn_mfma_f32_16x16x32_bf16(a0, bfr0[ks], ac0[h * 2 + 0], 0, 0, 0);
        ac1[h * 2 + 0] = __builtin_amdgcn_mfma_f32_16x16x32_bf16(a0, bfr1[ks], ac1[h * 2 + 0], 0, 0, 0);
        ac0[h * 2 + 1] = __builtin_amdgcn_mfma_f32_16x16x32_bf16(a1, bfr0[ks], ac0[h * 2 + 1], 0, 0, 0);
        ac1[h * 2 + 1] = __builtin_amdgcn_mfma_f32_16x16x32_bf16(a1, bfr1[ks], ac1[h * 2 + 1], 0, 0, 0);
      }
      __syncthreads();   // all waves done reading sW (WAR vs DMA below)
      // DMA next unit into the (single) buffer
      if (u < 15) {
        const uint4* sn = W2U(u + 1);
        uint4* dn = (uint4*)&sW[0];
#pragma unroll
        for (int j = 0; j < 4; ++j)
          gld_lds16(sn + tid + j * 256, dn + tid + j * 256);
      }
      if (h == 0) __syncthreads();   // drain DMA before next unit's MFMA
      // at h==1 the drain happens at the post-softmax barrier (softmax hides DMA)
    }

    // softmax per pixel group; taps 0..47 all valid (mt<3), tap 48 scalar on quad==0
    const float b48 = b_f2[c * 49 + 48];
#pragma unroll
    for (int g = 0; g < 2; ++g) {
      f32x4* ac = g ? ac1 : ac0;
      const float s = g ? s1v : s0v;
      float mx = -3.4e38f;
#pragma unroll
      for (int mt = 0; mt < 3; ++mt)
#pragma unroll
        for (int r = 0; r < 4; ++r) {
          const float lv = (ac[mt][r] + b_f2[c * 49 + mt * 16 + quad * 4 + r]) * s;
          ac[mt][r] = lv;
          mx = fmaxf(mx, lv);
        }
      const float v48 = (ac[3][0] + b48) * s;
      if (quad == 0) mx = fmaxf(mx, v48);
      mx = fmaxf(mx, __shfl_xor(mx, 16, 64));
      mx = fmaxf(mx, __shfl_xor(mx, 32, 64));
      float sum = 0.f;
#pragma unroll
      for (int mt = 0; mt < 3; ++mt)
#pragma unroll
        for (int r = 0; r < 4; ++r) {
          const float e = __expf(ac[mt][r] - mx);
          ac[mt][r] = e;
          sum += e;
        }
      const float e48 = (quad == 0) ? __expf(v48 - mx) : 0.f;
      sum += e48;
      sum += __shfl_xor(sum, 16, 64);
      sum += __shfl_xor(sum, 32, 64);
      const float rs = 1.f / sum;

      const int px = wave * 16 + n16 + g * 64;
#pragma unroll
      for (int mt = 0; mt < 3; ++mt)
#pragma unroll
        for (int r = 0; r < 4; ++r)
          sT[mt * 16 + quad * 4 + r][px] = f2bf(ac[mt][r] * rs);
      if (quad == 0) sT[48][px] = f2bf(e48 * rs);
    }
    __syncthreads();   // drains the h==1 DMA + sT visible

    // contiguous store: one 12.25 KB block per (b,c,row) = 784 uint4
    __hip_bfloat16* wob = wout + ((size_t)((ob * 24 + c) * 128 + row)) * 6272;
    for (int e = tid; e < 784; e += 256) {
      const int tap = e >> 4, qq = e & 15;
      *(uint4*)(wob + tap * 128 + qq * 8) = *(const uint4*)&sT[tap][qq * 8];
    }
    // WAR on sT: next channel's softmax writes happen after >=2 in-loop barriers
  }
#undef W2U
}

// ---------------- diffusion step v5: row-major weights (proven) ----------
__global__ __launch_bounds__(256) void diff_kernel(
    const float* __restrict__ lin, const __hip_bfloat16* __restrict__ wts,
    float* __restrict__ lout)
{
  __shared__ float sT[22][136];   // 16+6 rows, 128+6 cols (136: row 16B-aligned)
  const int bc = blockIdx.y;
  const int h0 = blockIdx.x * 16;
  const int tid = threadIdx.x;
  for (int e = tid; e < 22 * 134; e += 256) {
    int y = e / 134, x = e - y * 134;
    int gh = min(max(h0 - 3 + y, 0), 127), gw = min(max(x - 3, 0), 127);
    sT[y][x] = lin[(bc << 14) + (gh << 7) + gw];
  }
  __syncthreads();
  const int tx8 = (tid & 15) * 8;  // first of 8 pixels in w
  const int ty = tid >> 4;         // row 0..15
  const int h = h0 + ty;
  const __hip_bfloat16* wp = wts + ((size_t)(bc * 128 + h)) * 6272 + tx8;
  float a[8];
#pragma unroll
  for (int j = 0; j < 8; ++j) a[j] = 0.f;
#pragma unroll
  for (int kh = 0; kh < 7; ++kh) {
    const float* row = &sT[ty + kh][tx8];
    float r[16];
    *(f32x4*)&r[0]  = *(const f32x4*)(row);
    *(f32x4*)&r[4]  = *(const f32x4*)(row + 4);
    *(f32x4*)&r[8]  = *(const f32x4*)(row + 8);
    *(f32x4*)&r[12] = *(const f32x4*)(row + 12);
#pragma unroll
    for (int kw = 0; kw < 7; ++kw) {
      const int t = kh * 7 + kw;
      const uint4 wq = *(const uint4*)(wp + t * 128);
      a[0] = fmaf(bflo(wq.x), r[kw + 0], a[0]);
      a[1] = fmaf(bfhi(wq.x), r[kw + 1], a[1]);
      a[2] = fmaf(bflo(wq.y), r[kw + 2], a[2]);
      a[3] = fmaf(bfhi(wq.y), r[kw + 3], a[3]);
      a[4] = fmaf(bflo(wq.z), r[kw + 4], a[4]);
      a[5] = fmaf(bfhi(wq.z), r[kw + 5], a[5]);
      a[6] = fmaf(bflo(wq.w), r[kw + 6], a[6]);
      a[7] = fmaf(bfhi(wq.w), r[kw + 7], a[7]);
    }
  }
  float* dst = lout + (bc << 14) + (h << 7) + tx8;
  *(f32x4*)dst       = f32x4{a[0], a[1], a[2], a[3]};
  *(f32x4*)(dst + 4) = f32x4{a[4], a[5], a[6], a[7]};
}

// ---------------- orchestration ----------------
extern "C" void kernel_launch(void* const* d_in, const int* in_sizes, int n_in,
                              void* d_out, int out_size, void* d_ws, size_t ws_size,
                              hipStream_t stream)
{
  const float* depth = (const float*)d_in[0];
  const float* texf  = (const float*)d_in[1];
  const int*   labels= (const int*)d_in[2];
  const float* w_te1 = (const float*)d_in[3];
  const float* b_te1 = (const float*)d_in[4];
  const float* w_te2 = (const float*)d_in[5];
  const float* b_te2 = (const float*)d_in[6];
  const float* emb   = (const float*)d_in[7];
  const float* w_f1  = (const float*)d_in[8];
  const float* b_f1  = (const float*)d_in[9];
  const float* w_f2  = (const float*)d_in[10];
  const float* b_f2  = (const float*)d_in[11];
  const float* w_g1  = (const float*)d_in[12];
  const float* b_g1  = (const float*)d_in[13];
  const float* w_g2  = (const float*)d_in[14];
  const float* b_g2  = (const float*)d_in[15];
  const float* ci    = (const float*)d_in[16];

  char*  ws  = (char*)d_ws;
  float* wsf = (float*)d_ws;
  __hip_bfloat16* w2bf  = (__hip_bfloat16*)(ws + BO_W2B);
  __hip_bfloat16* te2bf = (__hip_bfloat16*)(ws + BO_TE2B);
  __hip_bfloat16* g1bf  = (__hip_bfloat16*)(ws + BO_WG1B);
  __hip_bfloat16* f1bf  = (__hip_bfloat16*)(ws + BO_WF1B);
  __hip_bfloat16* tex   = (__hip_bfloat16*)(ws + BO_TEX);
  __hip_bfloat16* f1    = (__hip_bfloat16*)(ws + BO_F1);
  float* ping           = (float*)(ws + BO_PING);
  float* pong           = (float*)(ws + BO_PONG);
  __hip_bfloat16* wts   = (__hip_bfloat16*)(ws + BO_W);
  __hip_bfloat16* t1    = (__hip_bfloat16*)(ws + BO_T1);

  float* out      = (float*)d_out;
  float* out_enh  = out;                 // [4][24][128][128]
  float* out_cg   = out + 1572864;       // [4][6][128][128]
  float* out_cond = out + 1966080;       // [4][1][128][128]

  prep_kernel<<<512, 256, 0, stream>>>(w_te1, w_te2, w_g1, w_f1, w_f2, w_g2, emb, labels, wsf);
  conv3x3_kernel<float, 3, true><<<dim3(64, 2, 4), 256, 0, stream>>>(texf, wsf + O_WTE1, b_te1, t1, 64);
  conv3x3_mfma_kernel<64,  false, false><<<dim3(64, 2, 4), 256, 0, stream>>>(
      t1, te2bf, b_te2, nullptr, tex, 128,
      nullptr, nullptr, nullptr, nullptr, nullptr, nullptr, nullptr);
  // gate1 conv + fused gate2
  conv3x3_mfma_kernel<128, false, true><<<dim3(64, 1, 4), 256, 0, stream>>>(
      tex, g1bf, b_g1, nullptr, nullptr, 64,
      wsf + O_WG2, b_g2, labels, ci, out_cg, out_cond, wsf + O_INT);
  conv3x3_mfma_kernel<128, true, false><<<dim3(64, 4, 4), 256, 0, stream>>>(
      tex, f1bf, b_f1, wsf + O_SS, f1, 256,
      nullptr, nullptr, nullptr, nullptr, nullptr, nullptr, nullptr);
  gemm_softmax_kernel<<<dim3(512, 3), 256, 0, stream>>>(f1, w2bf, b_f2, wsf + O_INT, wts);

  dim3 dgrid(8, 96);
  diff_kernel<<<dgrid, 256, 0, stream>>>(depth, wts, ping);
  diff_kernel<<<dgrid, 256, 0, stream>>>(ping, wts, pong);
  diff_kernel<<<dgrid, 256, 0, stream>>>(pong, wts, ping);
  diff_kernel<<<dgrid, 256, 0, stream>>>(ping, wts, pong);
  diff_kernel<<<dgrid, 256, 0, stream>>>(pong, wts, ping);
  diff_kernel<<<dgrid, 256, 0, stream>>>(ping, wts, pong);
  diff_kernel<<<dgrid, 256, 0, stream>>>(pong, wts, ping);
  diff_kernel<<<dgrid, 256, 0, stream>>>(ping, wts, out_enh);
}

// Round 11
// 487.101 us; speedup vs baseline: 1.3560x; 1.0001x over previous
//
#include <hip/hip_runtime.h>
#include <hip/hip_bf16.h>
#include <stdint.h>

#define DINL __device__ __forceinline__

DINL float bf2f(__hip_bfloat16 v) { return __bfloat162float(v); }
DINL __hip_bfloat16 f2bf(float v) { return __float2bfloat16(v); }
DINL float bflo(unsigned int u) { return __uint_as_float(u << 16); }
DINL float bfhi(unsigned int u) { return __uint_as_float(u & 0xffff0000u); }

DINL float loadf(float v) { return v; }
DINL float loadf(__hip_bfloat16 v) { return __bfloat162float(v); }

typedef __attribute__((ext_vector_type(8))) short bf16x8;
typedef __attribute__((ext_vector_type(4))) float f32x4;

// async global->LDS DMA, 16 B per lane. LDS dest must be wave-uniform base + lane*16
// (true for all call sites: addresses are base + tid*16 + const).
DINL void gld_lds16(const void* g, void* l) {
  __builtin_amdgcn_global_load_lds(
      (const __attribute__((address_space(1))) unsigned int*)g,
      (__attribute__((address_space(3))) unsigned int*)l, 16, 0, 0);
}

// ---------------- ws layout ----------------
// fp32 region (float offsets):
#define O_WTE1 0         // [2][3][9][32] fp32 blocked (te1 VALU conv)   1728
#define O_WG2  1792      // [6][64]                                      384
#define O_SS   2304      // [4][256][9]  border-class emb sums           9216
#define O_INT  11520     // [4][16384] intensity                         65536
// fp32 region ends at float 77056 = byte 308224
// bf16/byte offsets:
#define BO_W2B   308224u   // w_f2 bf16 MFMA *A-fragment* layout [24][4][8][64][8]  786432 B
#define BO_TE2B 1094656u   // w_te2 bf16 [2][2][9][64][32]      147456 B
#define BO_WG1B 1242112u   // w_g1  bf16 [1][4][9][64][32]      147456 B
#define BO_WF1B 1389568u   // w_f1  bf16 [4][4][9][64][32]      589824 B (ends 1979392)
#define BO_TEX  4194304u   // tex bf16 pixel-major [4][16384][128]  16.78 MB
#define BO_F1   20971520u  // f1  bf16 pixel-major [4][16384][256]  33.55 MB
#define BO_PING 54525952u  // fp32 [4*24*16384]  6.29 MB
#define BO_PONG 60817408u
#define BO_W    67108864u  // weights bf16 [4*24][row>>2][49 tap][row&3][128 w]  154.14 MB
                           // (v18: wave-contiguous 1 KB per tap per 4-row group)
#define BO_T1   BO_W             // t1 bf16 pixel-major [4][16384][64] (dead before W written)

// ---------------- prep: weight re-layouts (bf16 MFMA blocks) + SS table ----------------
__global__ __launch_bounds__(256) void prep_kernel(
    const float* __restrict__ w_te1, const float* __restrict__ w_te2,
    const float* __restrict__ w_g1,  const float* __restrict__ w_f1,
    const float* __restrict__ w_f2,  const float* __restrict__ w_g2,
    const float* __restrict__ emb,   const int* __restrict__ labels,
    float* __restrict__ wsf)
{
  const int gid = blockIdx.x * 256 + threadIdx.x;
  const int stride = gridDim.x * 256;
  const int A0 = 1728, A1 = A0 + 393216, A2 = A1 + 73728, A3 = A2 + 73728,
            A4 = A3 + 294912, A5 = A4 + 384;
  __hip_bfloat16* w2b  = (__hip_bfloat16*)((char*)wsf + BO_W2B);
  __hip_bfloat16* te2b = (__hip_bfloat16*)((char*)wsf + BO_TE2B);
  __hip_bfloat16* g1b  = (__hip_bfloat16*)((char*)wsf + BO_WG1B);
  __hip_bfloat16* f1b  = (__hip_bfloat16*)((char*)wsf + BO_WF1B);
  for (int i = gid; i < A5; i += stride) {
    if (i < A0) {
      int s = i; int o = s / 27; int r = s - o * 27; int ic = r / 9; int t = r - ic * 9;
      wsf[O_WTE1 + (((o >> 5) * 3 + ic) * 9 + t) * 32 + (o & 31)] = w_te1[s];
    } else if (i < A1) {
      // w_f2 [1176][256] fp32 -> bf16 A-fragment layout [c24][mt4][ks8][lane64][8]
      int s = i - A0;
      int j = s & 7; int lane = (s >> 3) & 63; int ks = (s >> 9) & 7;
      int mt = (s >> 12) & 3; int c = s >> 14;
      int tap = mt * 16 + (lane & 15);
      int k = ks * 32 + (lane >> 4) * 8 + j;
      float v = (tap < 49) ? w_f2[(c * 49 + tap) * 256 + k] : 0.f;
      w2b[s] = f2bf(v);
    } else if (i < A2) {
      int s = i - A1;
      int k = s & 31; int n = (s >> 5) & 63; int u = s >> 11;
      int t = u % 9; int v = u / 9; int kc = v & 1; int ocg = v >> 1;
      te2b[s] = f2bf(w_te2[((ocg * 64 + n) * 64 + kc * 32 + k) * 9 + t]);
    } else if (i < A3) {
      int s = i - A2;
      int k = s & 31; int n = (s >> 5) & 63; int u = s >> 11;
      int t = u % 9; int kc = u / 9;
      g1b[s] = f2bf(w_g1[(n * 128 + kc * 32 + k) * 9 + t]);
    } else if (i < A4) {
      int s = i - A3;
      int k = s & 31; int n = (s >> 5) & 63; int u = s >> 11;
      int t = u % 9; int v = u / 9; int kc = v & 3; int ocg = v >> 2;
      f1b[s] = f2bf(w_f1[((ocg * 64 + n) * 256 + kc * 32 + k) * 9 + t]);
    } else {
      int s = i - A4;
      wsf[O_WG2 + s] = w_g2[s];
    }
  }
  // SS: 16 slots per (b,o); slot s sums i in [s*8, s*8+8); shfl-reduce across slots.
  if (gid < 16384) {
    const int g = gid >> 4, slot = gid & 15;
    const int b = g >> 8, o = g & 255;
    const int lab = labels[b];
    float St[9];
#pragma unroll
    for (int t = 0; t < 9; ++t) St[t] = 0.f;
#pragma unroll 2
    for (int k = 0; k < 8; ++k) {
      const int i = slot * 8 + k;
      const float e = emb[lab * 128 + i];
      const float* wr = w_f1 + (size_t)(o * 256 + 128 + i) * 9;
#pragma unroll
      for (int t = 0; t < 9; ++t) St[t] += wr[t] * e;
    }
#pragma unroll
    for (int d = 1; d < 16; d <<= 1)
#pragma unroll
      for (int t = 0; t < 9; ++t) St[t] += __shfl_xor(St[t], d, 64);
    if (slot == 0) {
#pragma unroll
      for (int ch = 0; ch < 3; ++ch)
#pragma unroll
        for (int cw = 0; cw < 3; ++cw) {
          float sum = 0.f;
#pragma unroll
          for (int t = 0; t < 9; ++t) {
            int kh = t / 3, kw = t - kh * 3;
            bool ok = !(ch == 0 && kh == 0) && !(ch == 2 && kh == 2) &&
                      !(cw == 0 && kw == 0) && !(cw == 2 && kw == 2);
            if (ok) sum += St[t];
          }
          wsf[O_SS + g * 9 + ch * 3 + cw] = sum;
        }
    }
  }
}

// ---------------- small VALU 3x3 conv (te1 only: ICH=3) ----------------
template<typename TIn, int ICH, bool PIXMAJOR>
__global__ __launch_bounds__(256, 2) void conv3x3_kernel(
    const TIn* __restrict__ in, const float* __restrict__ wf,
    const float* __restrict__ bias,
    __hip_bfloat16* __restrict__ out, const int och_total)
{
  constexpr int CH = (ICH < 16) ? ICH : 16;
  constexpr int NCHUNK = ICH / CH;
  __shared__ TIn sIn[CH][18][20];
  const int tid = threadIdx.x;
  const int b = blockIdx.z;
  const int ob = blockIdx.y;
  const int och0 = ob * 32;
  const int tileY = blockIdx.x >> 3, tileX = blockIdx.x & 7;
  const int ty = tid >> 4, tx = tid & 15;
  const int h = tileY * 16 + ty, w = tileX * 16 + tx;
  const int h0 = tileY * 16 - 1, w0 = tileX * 16 - 1;

  float acc[32];
#pragma unroll
  for (int o = 0; o < 32; ++o) acc[o] = bias[och0 + o];

  for (int cc = 0; cc < NCHUNK; ++cc) {
    if (cc) __syncthreads();
    for (int e = tid; e < CH * 324; e += 256) {
      int ic = e / 324, r = e - ic * 324;
      int y = r / 18, x = r - y * 18;
      int gh = h0 + y, gw = w0 + x;
      TIn v = TIn(0.f);
      if ((unsigned)gh < 128u && (unsigned)gw < 128u)
        v = in[((b * ICH + cc * CH + ic) << 14) + (gh << 7) + gw];
      sIn[ic][y][x] = v;
    }
    __syncthreads();
#pragma unroll 1
    for (int ic = 0; ic < CH; ++ic) {
      const float* wrow = wf + (ob * ICH + cc * CH + ic) * 288;  // [9][32]
#pragma unroll
      for (int t = 0; t < 9; ++t) {
        const int kh = t / 3, kw = t - kh * 3;
        const float v = loadf(sIn[ic][ty + kh][tx + kw]);
#pragma unroll
        for (int o = 0; o < 32; ++o)
          acc[o] = fmaf(wrow[t * 32 + o], v, acc[o]);
      }
    }
  }

  const int pix = (h << 7) + w;
  if constexpr (!PIXMAJOR) {
#pragma unroll
    for (int o = 0; o < 32; ++o)
      out[((b * och_total + och0 + o) << 14) + pix] = f2bf(fmaxf(acc[o], 0.f));
  } else {
    union { uint4 u4[4]; __hip_bfloat16 hh[32]; } pk;
#pragma unroll
    for (int o = 0; o < 32; ++o) pk.hh[o] = f2bf(fmaxf(acc[o], 0.f));
    uint4* dst = reinterpret_cast<uint4*>(out + ((size_t)(b << 14) + pix) * och_total + och0);
#pragma unroll
    for (int i = 0; i < 4; ++i) dst[i] = pk.u4[i];
  }
}

// ---------------- MFMA implicit-GEMM 3x3 conv (zero pad), pixel-major bf16 ----------------
template<int ICH, bool ADD_SS, bool GATE>
__global__ __launch_bounds__(256, 2) void conv3x3_mfma_kernel(
    const __hip_bfloat16* __restrict__ in, const __hip_bfloat16* __restrict__ wb,
    const float* __restrict__ bias, const float* __restrict__ SS,
    __hip_bfloat16* __restrict__ out, const int och_total,
    const float* __restrict__ wg2, const float* __restrict__ b_g2,
    const int* __restrict__ labels, const float* __restrict__ ci,
    float* __restrict__ out_cg, float* __restrict__ out_cond,
    float* __restrict__ inten)
{
  constexpr int NKC = ICH / 32;
  __shared__ __hip_bfloat16 smem[36000];   // sH 324*40 | sW 9*64*40  (72 KB)
#define SHX(pos, k) smem[(pos) * 40 + (k)]
#define SWX(t, n, k) smem[12960 + (((t) * 64 + (n)) * 40) + (k)]
  const int tid = threadIdx.x, b = blockIdx.z, ocg = blockIdx.y;
  const int tileY = blockIdx.x >> 3, tileX = blockIdx.x & 7;
  const int h0 = tileY * 16 - 1, w0 = tileX * 16 - 1;
  const int wave = tid >> 6, lane = tid & 63, m16 = lane & 15, quad = lane >> 4;

  f32x4 acc[4][4];
#pragma unroll
  for (int i = 0; i < 4; ++i)
#pragma unroll
    for (int j = 0; j < 4; ++j) acc[i][j] = f32x4{0.f, 0.f, 0.f, 0.f};

  for (int kc = 0; kc < NKC; ++kc) {
    if (kc) __syncthreads();
    for (int e = tid; e < 1296; e += 256) {
      int pos = e >> 2, q = e & 3;
      int y = pos / 18, x = pos - y * 18;
      int gh = h0 + y, gw = w0 + x;
      uint4 v = uint4{0u, 0u, 0u, 0u};
      if ((unsigned)gh < 128u && (unsigned)gw < 128u)
        v = *(const uint4*)(in + ((size_t)((b << 14) + (gh << 7) + gw)) * ICH + kc * 32 + q * 8);
      *(uint4*)&SHX(pos, q * 8) = v;
    }
    const uint4* wsrc = (const uint4*)(wb + ((size_t)(ocg * NKC + kc)) * 9 * 64 * 32);
    for (int e = tid; e < 2304; e += 256) {
      int q = e & 3, n = (e >> 2) & 63, t = e >> 8;
      *(uint4*)&SWX(t, n, q * 8) = wsrc[e];
    }
    __syncthreads();
#pragma unroll
    for (int t = 0; t < 9; ++t) {
      const int dy = t / 3, dx = t - dy * 3;
      bf16x8 bfr[4];
#pragma unroll
      for (int nt = 0; nt < 4; ++nt)
        bfr[nt] = *(const bf16x8*)&SWX(t, nt * 16 + m16, quad * 8);
#pragma unroll
      for (int mi = 0; mi < 4; ++mi) {
        const int py = wave * 4 + mi;
        const bf16x8 afr = *(const bf16x8*)&SHX((py + dy) * 18 + dx + m16, quad * 8);
#pragma unroll
        for (int nt = 0; nt < 4; ++nt)
          acc[mi][nt] = __builtin_amdgcn_mfma_f32_16x16x32_bf16(afr, bfr[nt], acc[mi][nt], 0, 0, 0);
      }
    }
  }

  float bv[4];
#pragma unroll
  for (int nt = 0; nt < 4; ++nt) bv[nt] = bias[ocg * 64 + nt * 16 + m16];

  if constexpr (GATE) {
    __syncthreads();   // all MFMA smem reads done
    __hip_bfloat16* sG = smem;
#pragma unroll
    for (int mi = 0; mi < 4; ++mi)
#pragma unroll
      for (int nt = 0; nt < 4; ++nt) {
        const int och = nt * 16 + m16;
#pragma unroll
        for (int r = 0; r < 4; ++r) {
          const int p = (wave * 4 + mi) * 16 + quad * 4 + r;
          sG[p * 68 + och] = f2bf(fmaxf(acc[mi][nt][r] + bv[nt], 0.f));
        }
      }
    __syncthreads();
    const int p = tid;
    float a6[6];
#pragma unroll
    for (int k = 0; k < 6; ++k) a6[k] = b_g2[k];
#pragma unroll
    for (int i8 = 0; i8 < 8; ++i8) {
      const bf16x8 v8 = *(const bf16x8*)&sG[p * 68 + i8 * 8];
#pragma unroll
      for (int j = 0; j < 8; ++j) {
        const float v = bf2f(((const __hip_bfloat16*)&v8)[j]);
#pragma unroll
        for (int k = 0; k < 6; ++k)
          a6[k] = fmaf(wg2[k * 64 + i8 * 8 + j], v, a6[k]);
      }
    }
    const int lab = labels[b];
    float gate[6], gl = 0.f;
#pragma unroll
    for (int k = 0; k < 6; ++k) {
      gate[k] = 1.f / (1.f + __expf(-a6[k]));
      gl = (k == lab) ? gate[k] : gl;
    }
    const float civ = ci[lab];
    const float it = gl * civ;
    const int h = tileY * 16 + (p >> 4), w = tileX * 16 + (p & 15);
    const int pix = (h << 7) + w;
#pragma unroll
    for (int k = 0; k < 6; ++k)
      out_cg[((b * 6 + k) << 14) + pix] = (k == lab) ? gate[k] : 0.f;
    inten[(b << 14) + pix] = it;
    out_cond[(b << 14) + pix] = it * gl;
    return;
  }

#pragma unroll
  for (int mi = 0; mi < 4; ++mi) {
    const int py = wave * 4 + mi;
    const int h = tileY * 16 + py;
    const int chc = (h == 0) ? 0 : ((h == 127) ? 2 : 1);
#pragma unroll
    for (int nt = 0; nt < 4; ++nt) {
      float sr0 = 0.f, sr1 = 0.f, sr2 = 0.f;
      if constexpr (ADD_SS) {
        const float* sp = SS + ((size_t)(b << 8) + (ocg * 64 + nt * 16 + m16)) * 9;
        sr0 = sp[chc * 3 + 0]; sr1 = sp[chc * 3 + 1]; sr2 = sp[chc * 3 + 2];
      }
      const int och = ocg * 64 + nt * 16 + m16;
#pragma unroll
      for (int r = 0; r < 4; ++r) {
        const int px = quad * 4 + r;
        const int w = tileX * 16 + px;
        float v = acc[mi][nt][r] + bv[nt];
        if constexpr (ADD_SS)
          v += (w == 0) ? sr0 : ((w == 127) ? sr2 : sr1);
        v = fmaxf(v, 0.f);
        out[((size_t)((b << 14) + (h << 7) + w)) * och_total + och] = f2bf(v);
      }
    }
  }
#undef SHX
#undef SWX
}

// ---------------- fused GEMM+softmax v18: v17 (90 us) + wave-contiguous W store ----
// R25: v17 confirmed occupancy 28->34% gains ~1.5% -> gemm pinned at ~90.
// v18 changes ONLY the wts layout to [bc][row>>2][tap][row&3][128] so a diff
// wave's 64 lanes x 16 B per tap form exactly 1 KB CONTIGUOUS (the guide's ideal
// coalescing: one VMEM = 1 KB), and sequential taps walk one 49 KB sequential
// stream per wave-rowgroup — vs v12's 4 interleaved 256 B-granule streams.
// Decisive experiment for diff's 4.0 TB/s plateau (5 prior variants all neutral).
__global__ __launch_bounds__(256, 4) void gemm_softmax_kernel(
    const __hip_bfloat16* __restrict__ f1, const __hip_bfloat16* __restrict__ w2b,
    const float* __restrict__ b_f2, const float* __restrict__ inten,
    __hip_bfloat16* __restrict__ wout)
{
  __shared__ __hip_bfloat16 sW[8192];          // 16 KB: [mtl2][ks8][lane64][8]
  __shared__ __hip_bfloat16 sT[49][136];       // softmax out: [tap][pix] (+8 pad)
  const int tid = threadIdx.x;
  const int pix0 = blockIdx.x * 128;           // one (b,row): 128 px
  const int c0 = blockIdx.y * 8;                 // 8 channels per block
  const int wave = tid >> 6, lane = tid & 63;
  const int n16 = lane & 15, quad = lane >> 4;
  const int p0 = pix0 + wave * 16 + n16;         // pixel group 0
  const int p1 = p0 + 64;                        // pixel group 1

  // B fragments (f1, channel-invariant): 2 pixel groups x 8 ks-steps (64 VGPR)
  bf16x8 bfr0[8], bfr1[8];
#pragma unroll
  for (int ks = 0; ks < 8; ++ks) {
    bfr0[ks] = *(const bf16x8*)(f1 + (size_t)p0 * 256 + ks * 32 + quad * 8);
    bfr1[ks] = *(const bf16x8*)(f1 + (size_t)p1 * 256 + ks * 32 + quad * 8);
  }

  const float s0v = inten[p0], s1v = inten[p1];
  const int ob = pix0 >> 14, row = (pix0 >> 7) & 127;

  // unit u (0..15) = channel c0+(u>>1), mt-pair (u&1): 16 KB at w2b + unit<<12 elems
#define W2U(u) ((const uint4*)(w2b + ((((size_t)c0 + ((u) >> 1)) * 4 + (((u) & 1) << 1)) << 12)))

  // prologue: DMA unit 0
  {
    const uint4* s0 = W2U(0);
    uint4* d0 = (uint4*)&sW[0];
#pragma unroll
    for (int j = 0; j < 4; ++j)
      gld_lds16(s0 + tid + j * 256, d0 + tid + j * 256);
  }
  __syncthreads();   // drain: buf holds unit 0

#pragma unroll 1
  for (int cl = 0; cl < 8; ++cl) {
    const int c = c0 + cl;
    f32x4 ac0[4], ac1[4];
#pragma unroll
    for (int mt = 0; mt < 4; ++mt) { ac0[mt] = f32x4{0.f,0.f,0.f,0.f}; ac1[mt] = f32x4{0.f,0.f,0.f,0.f}; }

#pragma unroll
    for (int h = 0; h < 2; ++h) {
      const int u = cl * 2 + h;
      // compute unit u (mt = 2h, 2h+1) from sW: 32 MFMA
#pragma unroll
      for (int ks = 0; ks < 8; ++ks) {
        const bf16x8 a0 = *(const bf16x8*)(&sW[0] + ((ks) * 64 + lane) * 8);
        const bf16x8 a1 = *(const bf16x8*)(&sW[0] + ((8 + ks) * 64 + lane) * 8);
        ac0[h * 2 + 0] = __builtin_amdgcn_mfma_f32_16x16x32_bf16(a0, bfr0[ks], ac0[h * 2 + 0], 0, 0, 0);
        ac1[h * 2 + 0] = __builtin_amdgcn_mfma_f32_16x16x32_bf16(a0, bfr1[ks], ac1[h * 2 + 0], 0, 0, 0);
        ac0[h * 2 + 1] = __builtin_amdgcn_mfma_f32_16x16x32_bf16(a1, bfr0[ks], ac0[h * 2 + 1], 0, 0, 0);
        ac1[h * 2 + 1] = __builtin_amdgcn_mfma_f32_16x16x32_bf16(a1, bfr1[ks], ac1[h * 2 + 1], 0, 0, 0);
      }
      __syncthreads();   // all waves done reading sW (WAR vs DMA below)
      // DMA next unit into the (single) buffer
      if (u < 15) {
        const uint4* sn = W2U(u + 1);
        uint4* dn = (uint4*)&sW[0];
#pragma unroll
        for (int j = 0; j < 4; ++j)
          gld_lds16(sn + tid + j * 256, dn + tid + j * 256);
      }
      if (h == 0) __syncthreads();   // drain DMA before next unit's MFMA
      // at h==1 the drain happens at the post-softmax barrier (softmax hides DMA)
    }

    // softmax per pixel group; taps 0..47 all valid (mt<3), tap 48 scalar on quad==0
    const float b48 = b_f2[c * 49 + 48];
#pragma unroll
    for (int g = 0; g < 2; ++g) {
      f32x4* ac = g ? ac1 : ac0;
      const float s = g ? s1v : s0v;
      float mx = -3.4e38f;
#pragma unroll
      for (int mt = 0; mt < 3; ++mt)
#pragma unroll
        for (int r = 0; r < 4; ++r) {
          const float lv = (ac[mt][r] + b_f2[c * 49 + mt * 16 + quad * 4 + r]) * s;
          ac[mt][r] = lv;
          mx = fmaxf(mx, lv);
        }
      const float v48 = (ac[3][0] + b48) * s;
      if (quad == 0) mx = fmaxf(mx, v48);
      mx = fmaxf(mx, __shfl_xor(mx, 16, 64));
      mx = fmaxf(mx, __shfl_xor(mx, 32, 64));
      float sum = 0.f;
#pragma unroll
      for (int mt = 0; mt < 3; ++mt)
#pragma unroll
        for (int r = 0; r < 4; ++r) {
          const float e = __expf(ac[mt][r] - mx);
          ac[mt][r] = e;
          sum += e;
        }
      const float e48 = (quad == 0) ? __expf(v48 - mx) : 0.f;
      sum += e48;
      sum += __shfl_xor(sum, 16, 64);
      sum += __shfl_xor(sum, 32, 64);
      const float rs = 1.f / sum;

      const int px = wave * 16 + n16 + g * 64;
#pragma unroll
      for (int mt = 0; mt < 3; ++mt)
#pragma unroll
        for (int r = 0; r < 4; ++r)
          sT[mt * 16 + quad * 4 + r][px] = f2bf(ac[mt][r] * rs);
      if (quad == 0) sT[48][px] = f2bf(e48 * rs);
    }
    __syncthreads();   // drains the h==1 DMA + sT visible

    // store to wave-contiguous layout: elem off = (row>>2)*25088 + tap*512 + (row&3)*128 + px
    // per tap: 16 threads x 16 B = 256 B contiguous chunk (same coalescing as before)
    __hip_bfloat16* wob = wout + (size_t)(ob * 24 + c) * 802816
                               + (row >> 2) * 25088 + (row & 3) * 128;
    for (int e = tid; e < 784; e += 256) {
      const int tap = e >> 4, qq = e & 15;
      *(uint4*)(wob + tap * 512 + qq * 8) = *(const uint4*)&sT[tap][qq * 8];
    }
    // WAR on sT: next channel's softmax writes happen after >=2 in-loop barriers
  }
#undef W2U
}

// ---------------- diffusion step v6: wave-contiguous 1 KB weight reads ----------
// wts layout [bc][row>>2][tap][row&3][128]: a wave (ty 4w..4w+3, tx8 0..120) reads
// for tap t the 64x16 B = 1 KB contiguous block at rgbase + t*1024 B; sequential
// taps walk ONE 49 KB sequential stream per wave-rowgroup (ideal coalescing).
__global__ __launch_bounds__(256) void diff_kernel(
    const float* __restrict__ lin, const __hip_bfloat16* __restrict__ wts,
    float* __restrict__ lout)
{
  __shared__ float sT[22][136];   // 16+6 rows, 128+6 cols (136: row 16B-aligned)
  const int bc = blockIdx.y;
  const int h0 = blockIdx.x * 16;
  const int tid = threadIdx.x;
  for (int e = tid; e < 22 * 134; e += 256) {
    int y = e / 134, x = e - y * 134;
    int gh = min(max(h0 - 3 + y, 0), 127), gw = min(max(x - 3, 0), 127);
    sT[y][x] = lin[(bc << 14) + (gh << 7) + gw];
  }
  __syncthreads();
  const int tx8 = (tid & 15) * 8;  // first of 8 pixels in w
  const int ty = tid >> 4;         // row 0..15
  const int h = h0 + ty;
  // wave-contiguous weight base: [bc][h>>2][tap][h&3][128]
  const __hip_bfloat16* wp = wts + (size_t)bc * 802816
                                 + (h >> 2) * 25088 + (h & 3) * 128 + tx8;
  float a[8];
#pragma unroll
  for (int j = 0; j < 8; ++j) a[j] = 0.f;
#pragma unroll
  for (int kh = 0; kh < 7; ++kh) {
    const float* row = &sT[ty + kh][tx8];
    float r[16];
    *(f32x4*)&r[0]  = *(const f32x4*)(row);
    *(f32x4*)&r[4]  = *(const f32x4*)(row + 4);
    *(f32x4*)&r[8]  = *(const f32x4*)(row + 8);
    *(f32x4*)&r[12] = *(const f32x4*)(row + 12);
#pragma unroll
    for (int kw = 0; kw < 7; ++kw) {
      const int t = kh * 7 + kw;
      const uint4 wq = *(const uint4*)(wp + t * 512);
      a[0] = fmaf(bflo(wq.x), r[kw + 0], a[0]);
      a[1] = fmaf(bfhi(wq.x), r[kw + 1], a[1]);
      a[2] = fmaf(bflo(wq.y), r[kw + 2], a[2]);
      a[3] = fmaf(bfhi(wq.y), r[kw + 3], a[3]);
      a[4] = fmaf(bflo(wq.z), r[kw + 4], a[4]);
      a[5] = fmaf(bfhi(wq.z), r[kw + 5], a[5]);
      a[6] = fmaf(bflo(wq.w), r[kw + 6], a[6]);
      a[7] = fmaf(bfhi(wq.w), r[kw + 7], a[7]);
    }
  }
  float* dst = lout + (bc << 14) + (h << 7) + tx8;
  *(f32x4*)dst       = f32x4{a[0], a[1], a[2], a[3]};
  *(f32x4*)(dst + 4) = f32x4{a[4], a[5], a[6], a[7]};
}

// ---------------- orchestration ----------------
extern "C" void kernel_launch(void* const* d_in, const int* in_sizes, int n_in,
                              void* d_out, int out_size, void* d_ws, size_t ws_size,
                              hipStream_t stream)
{
  const float* depth = (const float*)d_in[0];
  const float* texf  = (const float*)d_in[1];
  const int*   labels= (const int*)d_in[2];
  const float* w_te1 = (const float*)d_in[3];
  const float* b_te1 = (const float*)d_in[4];
  const float* w_te2 = (const float*)d_in[5];
  const float* b_te2 = (const float*)d_in[6];
  const float* emb   = (const float*)d_in[7];
  const float* w_f1  = (const float*)d_in[8];
  const float* b_f1  = (const float*)d_in[9];
  const float* w_f2  = (const float*)d_in[10];
  const float* b_f2  = (const float*)d_in[11];
  const float* w_g1  = (const float*)d_in[12];
  const float* b_g1  = (const float*)d_in[13];
  const float* w_g2  = (const float*)d_in[14];
  const float* b_g2  = (const float*)d_in[15];
  const float* ci    = (const float*)d_in[16];

  char*  ws  = (char*)d_ws;
  float* wsf = (float*)d_ws;
  __hip_bfloat16* w2bf  = (__hip_bfloat16*)(ws + BO_W2B);
  __hip_bfloat16* te2bf = (__hip_bfloat16*)(ws + BO_TE2B);
  __hip_bfloat16* g1bf  = (__hip_bfloat16*)(ws + BO_WG1B);
  __hip_bfloat16* f1bf  = (__hip_bfloat16*)(ws + BO_WF1B);
  __hip_bfloat16* tex   = (__hip_bfloat16*)(ws + BO_TEX);
  __hip_bfloat16* f1    = (__hip_bfloat16*)(ws + BO_F1);
  float* ping           = (float*)(ws + BO_PING);
  float* pong           = (float*)(ws + BO_PONG);
  __hip_bfloat16* wts   = (__hip_bfloat16*)(ws + BO_W);
  __hip_bfloat16* t1    = (__hip_bfloat16*)(ws + BO_T1);

  float* out      = (float*)d_out;
  float* out_enh  = out;                 // [4][24][128][128]
  float* out_cg   = out + 1572864;       // [4][6][128][128]
  float* out_cond = out + 1966080;       // [4][1][128][128]

  prep_kernel<<<512, 256, 0, stream>>>(w_te1, w_te2, w_g1, w_f1, w_f2, w_g2, emb, labels, wsf);
  conv3x3_kernel<float, 3, true><<<dim3(64, 2, 4), 256, 0, stream>>>(texf, wsf + O_WTE1, b_te1, t1, 64);
  conv3x3_mfma_kernel<64,  false, false><<<dim3(64, 2, 4), 256, 0, stream>>>(
      t1, te2bf, b_te2, nullptr, tex, 128,
      nullptr, nullptr, nullptr, nullptr, nullptr, nullptr, nullptr);
  // gate1 conv + fused gate2
  conv3x3_mfma_kernel<128, false, true><<<dim3(64, 1, 4), 256, 0, stream>>>(
      tex, g1bf, b_g1, nullptr, nullptr, 64,
      wsf + O_WG2, b_g2, labels, ci, out_cg, out_cond, wsf + O_INT);
  conv3x3_mfma_kernel<128, true, false><<<dim3(64, 4, 4), 256, 0, stream>>>(
      tex, f1bf, b_f1, wsf + O_SS, f1, 256,
      nullptr, nullptr, nullptr, nullptr, nullptr, nullptr, nullptr);
  gemm_softmax_kernel<<<dim3(512, 3), 256, 0, stream>>>(f1, w2bf, b_f2, wsf + O_INT, wts);

  dim3 dgrid(8, 96);
  diff_kernel<<<dgrid, 256, 0, stream>>>(depth, wts, ping);
  diff_kernel<<<dgrid, 256, 0, stream>>>(ping, wts, pong);
  diff_kernel<<<dgrid, 256, 0, stream>>>(pong, wts, ping);
  diff_kernel<<<dgrid, 256, 0, stream>>>(ping, wts, pong);
  diff_kernel<<<dgrid, 256, 0, stream>>>(pong, wts, ping);
  diff_kernel<<<dgrid, 256, 0, stream>>>(ping, wts, pong);
  diff_kernel<<<dgrid, 256, 0, stream>>>(pong, wts, ping);
  diff_kernel<<<dgrid, 256, 0, stream>>>(ping, wts, out_enh);
}